// Round 1
// baseline (1901.435 us; speedup 1.0000x reference)
//
#include <hip/hip_runtime.h>
#include <hip/hip_bf16.h>

using bf16 = __hip_bfloat16;
typedef __attribute__((ext_vector_type(8))) short short8;
typedef __attribute__((ext_vector_type(4))) float f32x4;

#define NN 8192
#define DD 32
#define QQ 4096
#define CINN 128
#define CH 256
#define EE (NN*DD)
#define MBYTE ((size_t)1024*1024)

__device__ __forceinline__ short f2bf(float f){
  bf16 h = __float2bfloat16(f);
  return *reinterpret_cast<short*>(&h);
}

// ---------------- zero scratch ----------------
__global__ void k_zero(float* p1, int n1, float* p2, int n2){
  int i = blockIdx.x*256 + threadIdx.x;
  if (i < n1) p1[i] = 0.f;
  else if (i < n1 + n2) p2[i - n1] = 0.f;
}

// ---------------- weight convert+transpose: W (K x N f32) -> WT (N x K bf16) ----------------
__global__ void k_wconv(const float* __restrict__ W, bf16* __restrict__ WT, int K, int Ncols){
  int idx = blockIdx.x*256 + threadIdx.x;
  if (idx >= K*Ncols) return;
  int n = idx / K, k = idx - n*K;
  WT[idx] = __float2bfloat16(W[(size_t)k*Ncols + n]);
}

// ---------------- BN column stats (sum, sumsq) ----------------
__global__ void k_bnstats(const float* __restrict__ X, float* __restrict__ sums, int M, int C){
  int c = threadIdx.x;
  float s = 0.f, s2 = 0.f;
  for (int r = blockIdx.x; r < M; r += gridDim.x){
    float v = X[(size_t)r*C + c];
    s += v; s2 += v*v;
  }
  atomicAdd(&sums[c], s);
  atomicAdd(&sums[C+c], s2);
}

// ---------------- BN apply (mu/rsig computed inline) ----------------
__global__ void k_bnapply(const float* __restrict__ X, const float* __restrict__ sums,
                          const float* __restrict__ g, const float* __restrict__ b,
                          const float* __restrict__ addin, float* __restrict__ outf,
                          bf16* __restrict__ outb, int M, int Cm1, int relu){
  int idx = blockIdx.x*256 + threadIdx.x;
  int c = idx & Cm1;
  int C = Cm1 + 1;
  float mu = sums[c] / (float)M;
  float var = sums[C+c] / (float)M - mu*mu;
  float rs = rsqrtf(var + 1e-5f);
  float v = (X[idx] - mu)*rs*g[c] + b[c];
  if (addin) v += addin[idx];
  if (relu) v = fmaxf(v, 0.f);
  if (outf) outf[idx] = v;
  if (outb) outb[idx] = __float2bfloat16(v);
}

// ---------------- strip GEMM: C[M x Ncols] = A[M x K] @ BT^T, 1 wave = 16 rows ----------------
template<int KCH>
__global__ __launch_bounds__(64)
void k_gemm(const bf16* __restrict__ A, const bf16* __restrict__ BT,
            const float* __restrict__ bias, const float* __restrict__ resid,
            float* __restrict__ Cf, bf16* __restrict__ Cb,
            int Ncols, int ldc, int relu)
{
  constexpr int K = KCH*32;
  const int row0 = blockIdx.x*16;
  const int lane = threadIdx.x;
  const int lr = lane & 15, lg = lane >> 4;
  short8 af[KCH];
  const short* Arow = (const short*)A + (size_t)(row0+lr)*K + lg*8;
#pragma unroll
  for (int c2 = 0; c2 < KCH; c2++) af[c2] = *(const short8*)(Arow + c2*32);
  const int ntiles = Ncols >> 4;
  for (int ct = 0; ct < ntiles; ct++){
    f32x4 acc = {0.f,0.f,0.f,0.f};
    const short* Brow = (const short*)BT + (size_t)(ct*16+lr)*K + lg*8;
#pragma unroll
    for (int c2 = 0; c2 < KCH; c2++){
      short8 bfr = *(const short8*)(Brow + c2*32);
      acc = __builtin_amdgcn_mfma_f32_16x16x32_bf16(af[c2], bfr, acc, 0, 0, 0);
    }
    int col = ct*16 + lr;
    float bvv = bias ? bias[col] : 0.f;
#pragma unroll
    for (int r = 0; r < 4; r++){
      int row = row0 + lg*4 + r;
      size_t o = (size_t)row*ldc + col;
      float v = acc[r] + bvv;
      if (resid) v += resid[o];
      if (relu) v = fmaxf(v, 0.f);
      if (Cf) Cf[o] = v;
      if (Cb) Cb[o] = __float2bfloat16(v);
    }
  }
}

// ---------------- GCN pieces ----------------
__global__ void k_deg(const int* __restrict__ dst, const float* __restrict__ ew, float* __restrict__ deg){
  int e = blockIdx.x*256 + threadIdx.x;
  if (e < EE) atomicAdd(&deg[dst[e]], ew[e]);
}
__global__ void k_dinv(float* deg){
  int i = blockIdx.x*256 + threadIdx.x;
  if (i < NN) deg[i] = rsqrtf(deg[i] + 1.0f);
}
__global__ __launch_bounds__(256)
void k_agg(const int* __restrict__ src, const int* __restrict__ dst, const float* __restrict__ ew,
           const float* __restrict__ dinv, const float* __restrict__ hw, float* __restrict__ agg){
  int e = blockIdx.x*4 + (threadIdx.x >> 6);
  int lane = threadIdx.x & 63;
  if (e >= EE) return;
  int s = src[e], d = dst[e];
  float coef = dinv[s]*ew[e]*dinv[d];
  const f32x4* hr = (const f32x4*)(hw + (size_t)s*CH);
  f32x4 v = hr[lane];
  float* ad = agg + (size_t)d*CH + lane*4;
  atomicAdd(ad+0, v[0]*coef);
  atomicAdd(ad+1, v[1]*coef);
  atomicAdd(ad+2, v[2]*coef);
  atomicAdd(ad+3, v[3]*coef);
}
__global__ void k_y1(const float* __restrict__ agg, const float* __restrict__ hw,
                     const float* __restrict__ dinv, const float* __restrict__ bgcn,
                     const float* __restrict__ h, float* __restrict__ y1){
  int idx = blockIdx.x*256 + threadIdx.x;
  int i = idx >> 8, c = idx & 255;
  float di = dinv[i];
  y1[idx] = agg[idx] + hw[idx]*di*di + bgcn[c] + h[idx];
}

// ---------------- bf16 transpose 8192x256 -> 256x8192 ----------------
__global__ __launch_bounds__(256)
void k_transpose(const bf16* __restrict__ in, bf16* __restrict__ out){
  __shared__ short tile[32][33];
  int bx = blockIdx.x & 7;        // col tile (256/32)
  int by = blockIdx.x >> 3;       // row tile (8192/32)
  int tx = threadIdx.x & 31, ty = threadIdx.x >> 5;
  const short* inp = (const short*)in;
  short* outp = (short*)out;
#pragma unroll
  for (int i = 0; i < 4; i++)
    tile[ty + i*8][tx] = inp[(size_t)(by*32 + ty + i*8)*256 + bx*32 + tx];
  __syncthreads();
#pragma unroll
  for (int i = 0; i < 4; i++)
    outp[(size_t)(bx*32 + ty + i*8)*8192 + by*32 + tx] = tile[tx][ty + i*8];
}

// ---------------- flash attention: 4 waves x 16 queries, 2 key-splits ----------------
__global__ __launch_bounds__(256)
void k_attn(const bf16* __restrict__ Qm, const bf16* __restrict__ Km, const bf16* __restrict__ VT,
            float* __restrict__ Opart, float* __restrict__ Mpart, float* __restrict__ Lpart)
{
  __shared__ short sP[4][16*32];
  const int wid = threadIdx.x >> 6, lane = threadIdx.x & 63;
  const int lr = lane & 15, lg = lane >> 4;
  const int qblock = blockIdx.x >> 1, split = blockIdx.x & 1;
  const int q0 = qblock*64 + wid*16;
  const int k0base = split*4096;

  short8 qf[8];
  const short* Qrow = (const short*)Qm + (size_t)(q0+lr)*CH + lg*8;
#pragma unroll
  for (int c = 0; c < 8; c++) qf[c] = *(const short8*)(Qrow + c*32);

  f32x4 acc[16];
#pragma unroll
  for (int dt = 0; dt < 16; dt++) acc[dt] = {0.f,0.f,0.f,0.f};
  float m[4], lsum[4];
#pragma unroll
  for (int r = 0; r < 4; r++){ m[r] = -1e30f; lsum[r] = 0.f; }
  const float scale = 0.0625f; // 1/sqrt(256)

  for (int kt = 0; kt < 128; kt++){
    const int k0 = k0base + kt*32;
    f32x4 s0 = {0.f,0.f,0.f,0.f}, s1 = {0.f,0.f,0.f,0.f};
    const short* Krow0 = (const short*)Km + (size_t)(k0+lr)*CH + lg*8;
    const short* Krow1 = Krow0 + 16*CH;
#pragma unroll
    for (int c = 0; c < 8; c++){
      short8 kf0 = *(const short8*)(Krow0 + c*32);
      s0 = __builtin_amdgcn_mfma_f32_16x16x32_bf16(qf[c], kf0, s0, 0, 0, 0);
      short8 kf1 = *(const short8*)(Krow1 + c*32);
      s1 = __builtin_amdgcn_mfma_f32_16x16x32_bf16(qf[c], kf1, s1, 0, 0, 0);
    }
    // online softmax over these 32 keys; lane holds rows lg*4+r, key col lr / 16+lr
#pragma unroll
    for (int r = 0; r < 4; r++){
      float x0 = s0[r]*scale, x1 = s1[r]*scale;
      float pm = fmaxf(x0, x1);
#pragma unroll
      for (int off = 1; off < 16; off <<= 1) pm = fmaxf(pm, __shfl_xor(pm, off, 64));
      float mn = fmaxf(m[r], pm);
      float al = __expf(m[r] - mn);
      float p0 = __expf(x0 - mn), p1 = __expf(x1 - mn);
      float rsm = p0 + p1;
#pragma unroll
      for (int off = 1; off < 16; off <<= 1) rsm += __shfl_xor(rsm, off, 64);
      lsum[r] = lsum[r]*al + rsm;
      m[r] = mn;
#pragma unroll
      for (int dt = 0; dt < 16; dt++) acc[dt][r] *= al;
      int prow = lg*4 + r;
      sP[wid][prow*32 + lr]      = f2bf(p0);
      sP[wid][prow*32 + 16 + lr] = f2bf(p1);
    }
    __builtin_amdgcn_sched_barrier(0);
    // re-layout P into A-frag: row = lr (query), k = lg*8.. (key)
    short8 pf = *(const short8*)(&sP[wid][lr*32 + lg*8]);
    // PV: O += P @ V ; B-frag from VT rows (dims), contiguous keys
#pragma unroll
    for (int dt = 0; dt < 16; dt++){
      const short* Vrow = (const short*)VT + (size_t)(dt*16 + lr)*8192 + k0 + lg*8;
      short8 vf = *(const short8*)Vrow;
      acc[dt] = __builtin_amdgcn_mfma_f32_16x16x32_bf16(pf, vf, acc[dt], 0, 0, 0);
    }
  }
  size_t base = (size_t)split*NN*CH;
#pragma unroll
  for (int dt = 0; dt < 16; dt++){
#pragma unroll
    for (int r = 0; r < 4; r++){
      int row = q0 + lg*4 + r;
      Opart[base + (size_t)row*CH + dt*16 + lr] = acc[dt][r];
    }
  }
  if (lr == 0){
#pragma unroll
    for (int r = 0; r < 4; r++){
      int row = q0 + lg*4 + r;
      Mpart[split*NN + row] = m[r];
      Lpart[split*NN + row] = lsum[r];
    }
  }
}

__global__ void k_merge(const float* __restrict__ Opart, const float* __restrict__ Mp,
                        const float* __restrict__ Lp, bf16* __restrict__ out){
  int idx = blockIdx.x*256 + threadIdx.x;   // over NN*CH
  int q = idx >> 8;
  float m0 = Mp[q], m1 = Mp[NN+q], l0 = Lp[q], l1 = Lp[NN+q];
  float M = fmaxf(m0, m1);
  float w0 = __expf(m0 - M), w1 = __expf(m1 - M);
  float denom = l0*w0 + l1*w1;
  float v = (Opart[idx]*w0 + Opart[(size_t)NN*CH + idx]*w1) / denom;
  out[idx] = __float2bfloat16(v);
}

// ---------------- link-prediction head ----------------
__global__ void k_content(const int* __restrict__ eli, const float* __restrict__ z3, bf16* __restrict__ outc){
  int idx = blockIdx.x*256 + threadIdx.x;   // over QQ*CH
  int q = idx >> 8, c = idx & 255;
  int a = eli[q], b = eli[QQ + q];
  outc[idx] = __float2bfloat16(z3[(size_t)a*CH + c]*z3[(size_t)b*CH + c]);
}

__global__ __launch_bounds__(256)
void k_structure(const int* __restrict__ eli, const int* __restrict__ nbr,
                 const float* __restrict__ z3, const float* __restrict__ tptr, bf16* __restrict__ outs){
  __shared__ int tn[32];
  __shared__ int msk[32];
  int q = blockIdx.x;
  if (threadIdx.x < 32){
    int d = threadIdx.x;
    int a = nbr[(size_t)eli[q]*DD + d];       // t_nbr (neighbors of eli0)
    int s = nbr[(size_t)eli[QQ+q]*DD + d];    // s_nbr (neighbors of eli1)
    tn[d] = a;
    msk[d] = (a == s);
  }
  __syncthreads();
  int c = threadIdx.x;
  float tval = tptr[0];
  float vmax = -1e30f;
  float zg[32];
#pragma unroll
  for (int d = 0; d < 32; d++){
    float v = msk[d] ? z3[(size_t)tn[d]*CH + c] : 0.f;
    zg[d] = v;
    float sc = msk[d] ? tval*v : -1e30f;
    vmax = fmaxf(vmax, sc);
  }
  float esum = 0.f, wsum = 0.f;
#pragma unroll
  for (int d = 0; d < 32; d++){
    float e = msk[d] ? __expf(tval*zg[d] - vmax) : 0.f;
    esum += e;
    wsum += e*zg[d];
  }
  outs[(size_t)q*CH + c] = __float2bfloat16(wsum / fmaxf(esum, 1e-12f));
}

__global__ __launch_bounds__(256)
void k_final(const bf16* __restrict__ hmid, const float* __restrict__ w,
             const float* __restrict__ b, float* __restrict__ out){
  int r = blockIdx.x*4 + (threadIdx.x >> 6);
  int lane = threadIdx.x & 63;
  float s = 0.f;
#pragma unroll
  for (int i = 0; i < 4; i++){
    int c = lane + 64*i;
    s += __bfloat162float(hmid[(size_t)r*CH + c]) * w[c];
  }
#pragma unroll
  for (int off = 32; off; off >>= 1) s += __shfl_xor(s, off, 64);
  if (lane == 0) out[r] = s + b[0];
}

// =====================================================================
extern "C" void kernel_launch(void* const* d_in, const int* in_sizes, int n_in,
                              void* d_out, int out_size, void* d_ws, size_t ws_size,
                              hipStream_t stream)
{
  const float* x      = (const float*)d_in[0];
  const int*   eidx   = (const int*)d_in[1];
  const float* ew     = (const float*)d_in[2];
  const int*   eli    = (const int*)d_in[3];
  const int*   nbr    = (const int*)d_in[4];
  const float* pe_g   = (const float*)d_in[5];
  const float* pe_b   = (const float*)d_in[6];
  const float* W_pe   = (const float*)d_in[7];
  const float* b_pe   = (const float*)d_in[8];
  const float* W_gcn  = (const float*)d_in[9];
  const float* b_gcn  = (const float*)d_in[10];
  const float* bn1_g  = (const float*)d_in[11];
  const float* bn1_b  = (const float*)d_in[12];
  const float* Wq     = (const float*)d_in[13];
  const float* bq     = (const float*)d_in[14];
  const float* Wk     = (const float*)d_in[15];
  const float* bk     = (const float*)d_in[16];
  const float* Wv     = (const float*)d_in[17];
  const float* bvv    = (const float*)d_in[18];
  const float* Wo     = (const float*)d_in[19];
  const float* bo     = (const float*)d_in[20];
  const float* bn2_g  = (const float*)d_in[21];
  const float* bn2_b  = (const float*)d_in[22];
  const float* W_m1   = (const float*)d_in[23];
  const float* b_m1   = (const float*)d_in[24];
  const float* W_m2   = (const float*)d_in[25];
  const float* b_m2   = (const float*)d_in[26];
  const float* bn3_g  = (const float*)d_in[27];
  const float* bn3_b  = (const float*)d_in[28];
  const float* W_cm   = (const float*)d_in[29];
  const float* b_cm   = (const float*)d_in[30];
  const float* W_sm   = (const float*)d_in[31];
  const float* b_sm   = (const float*)d_in[32];
  const float* W_o1   = (const float*)d_in[33];
  const float* b_o1   = (const float*)d_in[34];
  const float* bno_g  = (const float*)d_in[35];
  const float* bno_b  = (const float*)d_in[36];
  const float* W_o2   = (const float*)d_in[37];
  const float* b_o2   = (const float*)d_in[38];
  const float* tptr   = (const float*)d_in[39];

  if (ws_size < 64*MBYTE) return;
  char* ws = (char*)d_ws;

  // weights (bf16, transposed) at [0, 1.75MB)
  bf16* WpeT  = (bf16*)(ws + 0);
  bf16* WgcnT = (bf16*)(ws + 64*1024);
  bf16* WqT   = (bf16*)(ws + 192*1024);
  bf16* WkT   = (bf16*)(ws + 320*1024);
  bf16* WvT   = (bf16*)(ws + 448*1024);
  bf16* WoT   = (bf16*)(ws + 576*1024);
  bf16* Wm1T  = (bf16*)(ws + 704*1024);
  bf16* Wm2T  = (bf16*)(ws + 960*1024);
  bf16* WcmT  = (bf16*)(ws + 1216*1024);
  bf16* WsmT  = (bf16*)(ws + 1344*1024);
  bf16* Wo1T  = (bf16*)(ws + 1472*1024);
  // small region at 2MB
  float* stat_x = (float*)(ws + 2*MBYTE);
  float* stat1  = (float*)(ws + 2*MBYTE + 1024);
  float* stat2  = (float*)(ws + 2*MBYTE + 3*1024);
  float* stat3  = (float*)(ws + 2*MBYTE + 5*1024);
  float* stato  = (float*)(ws + 2*MBYTE + 7*1024);
  float* deg    = (float*)(ws + 2*MBYTE + 16*1024);
  float* Mpart  = (float*)(ws + 2*MBYTE + 64*1024);
  float* Lpart  = (float*)(ws + 2*MBYTE + 128*1024);
  // big buffers (with manual lifetime reuse)
  bf16*  xn    = (bf16*)(ws + 4*MBYTE);     // 2MB; later: content
  float* hbuf  = (float*)(ws + 8*MBYTE);    // 8MB; later y2 in-place; later z3b+structure
  bf16*  hb    = (bf16*)(ws + 16*MBYTE);    // 4MB; later attn_bf16; later hcat
  float* hw    = (float*)(ws + 20*MBYTE);   // 8MB; later Opart[0]; later y3
  float* aggb  = (float*)(ws + 28*MBYTE);   // 8MB (also y1); later Opart[1]; later z3
  float* h1    = (float*)(ws + 36*MBYTE);   // 8MB; later y4 + hmid
  bf16*  qb    = (bf16*)(ws + 44*MBYTE);    // 4MB; later z_f32 (8MB over q,k)
  bf16*  kb    = (bf16*)(ws + 48*MBYTE);
  bf16*  vb    = (bf16*)(ws + 52*MBYTE);    // later z_bf16
  bf16*  vT    = (bf16*)(ws + 56*MBYTE);    // later mid (8MB)
  float* Opart = (float*)(ws + 20*MBYTE);
  bf16*  attnb = (bf16*)(ws + 16*MBYTE);
  float* y2    = hbuf;
  float* zf    = (float*)(ws + 44*MBYTE);
  bf16*  zb    = (bf16*)(ws + 52*MBYTE);
  bf16*  midb  = (bf16*)(ws + 56*MBYTE);
  float* y3    = (float*)(ws + 20*MBYTE);
  float* z3    = (float*)(ws + 28*MBYTE);
  bf16*  z3b   = (bf16*)(ws + 8*MBYTE);
  bf16*  contb = (bf16*)(ws + 4*MBYTE);
  bf16*  strub = (bf16*)(ws + 12*MBYTE);
  bf16*  hcat  = (bf16*)(ws + 16*MBYTE);
  float* y4    = (float*)(ws + 36*MBYTE);
  bf16*  hmid  = (bf16*)(ws + 40*MBYTE);

  const int* srcp = eidx;
  const int* dstp = eidx + EE;

  // zero stats+deg (48KB of floats) and agg
  k_zero<<<(12288 + NN*CH + 255)/256, 256, 0, stream>>>((float*)(ws + 2*MBYTE), 12288, aggb, NN*CH);

  // weight prep
  k_wconv<<<128, 256, 0, stream>>>(W_pe, WpeT, 128, 256);
  k_wconv<<<256, 256, 0, stream>>>(W_gcn, WgcnT, 256, 256);
  k_wconv<<<256, 256, 0, stream>>>(Wq, WqT, 256, 256);
  k_wconv<<<256, 256, 0, stream>>>(Wk, WkT, 256, 256);
  k_wconv<<<256, 256, 0, stream>>>(Wv, WvT, 256, 256);
  k_wconv<<<256, 256, 0, stream>>>(Wo, WoT, 256, 256);
  k_wconv<<<512, 256, 0, stream>>>(W_m1, Wm1T, 256, 512);
  k_wconv<<<512, 256, 0, stream>>>(W_m2, Wm2T, 512, 256);
  k_wconv<<<256, 256, 0, stream>>>(W_cm, WcmT, 256, 256);
  k_wconv<<<256, 256, 0, stream>>>(W_sm, WsmT, 256, 256);
  k_wconv<<<512, 256, 0, stream>>>(W_o1, Wo1T, 512, 256);

  // input BN -> xn (bf16)
  k_bnstats<<<256, 128, 0, stream>>>(x, stat_x, NN, CINN);
  k_bnapply<<<NN*CINN/256, 256, 0, stream>>>(x, stat_x, pe_g, pe_b, nullptr, nullptr, xn, NN, CINN-1, 0);

  // h = xn @ W_pe + b_pe  (f32 + bf16)
  k_gemm<4><<<NN/16, 64, 0, stream>>>(xn, WpeT, b_pe, nullptr, hbuf, hb, 256, 256, 0);

  // degrees
  k_deg<<<EE/256, 256, 0, stream>>>(dstp, ew, deg);
  k_dinv<<<NN/256, 256, 0, stream>>>(deg);

  // hw = h @ W_gcn
  k_gemm<8><<<NN/16, 64, 0, stream>>>(hb, WgcnT, nullptr, nullptr, hw, nullptr, 256, 256, 0);

  // agg scatter (atomics), then y1 = agg + hw*dinv^2 + b_gcn + h (in-place over agg)
  k_agg<<<EE/4, 256, 0, stream>>>(srcp, dstp, ew, deg, hw, aggb);
  k_y1<<<NN*CH/256, 256, 0, stream>>>(aggb, hw, deg, b_gcn, hbuf, aggb);

  // bn1 -> h1
  k_bnstats<<<256, 256, 0, stream>>>(aggb, stat1, NN, CH);
  k_bnapply<<<NN*CH/256, 256, 0, stream>>>(aggb, stat1, bn1_g, bn1_b, nullptr, h1, nullptr, NN, CH-1, 0);

  // q, k, v (bf16)
  k_gemm<8><<<NN/16, 64, 0, stream>>>(hb, WqT, bq, nullptr, nullptr, qb, 256, 256, 0);
  k_gemm<8><<<NN/16, 64, 0, stream>>>(hb, WkT, bk, nullptr, nullptr, kb, 256, 256, 0);
  k_gemm<8><<<NN/16, 64, 0, stream>>>(hb, WvT, bvv, nullptr, nullptr, vb, 256, 256, 0);
  k_transpose<<<2048, 256, 0, stream>>>(vb, vT);

  // attention (2 key-splits) + merge
  k_attn<<<256, 256, 0, stream>>>(qb, kb, vT, Opart, Mpart, Lpart);
  k_merge<<<NN*CH/256, 256, 0, stream>>>(Opart, Mpart, Lpart, attnb);

  // y2 = attn @ Wo + bo + h  (in-place over h)
  k_gemm<8><<<NN/16, 64, 0, stream>>>(attnb, WoT, bo, hbuf, hbuf, nullptr, 256, 256, 0);

  // z = h1 + bn2(y2)
  k_bnstats<<<256, 256, 0, stream>>>(y2, stat2, NN, CH);
  k_bnapply<<<NN*CH/256, 256, 0, stream>>>(y2, stat2, bn2_g, bn2_b, h1, zf, zb, NN, CH-1, 0);

  // mid = relu(z @ W_m1 + b_m1) (bf16), y3 = mid @ W_m2 + b_m2 + z
  k_gemm<8><<<NN/16, 64, 0, stream>>>(zb, Wm1T, b_m1, nullptr, nullptr, midb, 512, 512, 1);
  k_gemm<16><<<NN/16, 64, 0, stream>>>(midb, Wm2T, b_m2, zf, y3, nullptr, 256, 256, 0);

  // bn3 -> z3 (f32 + bf16)
  k_bnstats<<<256, 256, 0, stream>>>(y3, stat3, NN, CH);
  k_bnapply<<<NN*CH/256, 256, 0, stream>>>(y3, stat3, bn3_g, bn3_b, nullptr, z3, z3b, NN, CH-1, 0);

  // head: content & structure
  k_content<<<QQ*CH/256, 256, 0, stream>>>(eli, z3, contb);
  k_structure<<<QQ, 256, 0, stream>>>(eli, nbr, z3, tptr, strub);

  // hcat = [content@W_cm + b_cm | structure@W_sm + b_sm]  (bf16, ld=512)
  k_gemm<8><<<QQ/16, 64, 0, stream>>>(contb, WcmT, b_cm, nullptr, nullptr, hcat, 256, 512, 0);
  k_gemm<8><<<QQ/16, 64, 0, stream>>>(strub, WsmT, b_sm, nullptr, nullptr, hcat + 256, 256, 512, 0);

  // y4 = hcat @ W_o1 + b_o1 ; hmid = relu(bn_o(y4)) (bf16)
  k_gemm<16><<<QQ/16, 64, 0, stream>>>(hcat, Wo1T, b_o1, nullptr, y4, nullptr, 256, 256, 0);
  k_bnstats<<<256, 256, 0, stream>>>(y4, stato, QQ, CH);
  k_bnapply<<<QQ*CH/256, 256, 0, stream>>>(y4, stato, bno_g, bno_b, nullptr, nullptr, hmid, QQ, CH-1, 1);

  // out = hmid @ W_o2 + b_o2
  k_final<<<QQ/4, 256, 0, stream>>>(hmid, W_o2, b_o2, (float*)d_out);
}

// Round 2
// 1074.724 us; speedup vs baseline: 1.7692x; 1.7692x over previous
//
#include <hip/hip_runtime.h>
#include <hip/hip_bf16.h>

using bf16 = __hip_bfloat16;
typedef __attribute__((ext_vector_type(8))) short short8;
typedef __attribute__((ext_vector_type(4))) float f32x4;

#define NN 8192
#define DD 32
#define QQ 4096
#define CINN 128
#define CH 256
#define EE (NN*DD)
#define MBYTE ((size_t)1024*1024)

__device__ __forceinline__ short f2bf(float f){
  bf16 h = __float2bfloat16(f);
  return *reinterpret_cast<short*>(&h);
}

// ---------------- zero scratch ----------------
__global__ void k_zero(float* p1, int n1, float* p2, int n2){
  int i = blockIdx.x*256 + threadIdx.x;
  if (i < n1) p1[i] = 0.f;
  else if (i < n1 + n2) p2[i - n1] = 0.f;
}

// ---------------- weight convert+transpose: W (K x N f32) -> WT (N x K bf16) ----------------
__global__ void k_wconv(const float* __restrict__ W, bf16* __restrict__ WT, int K, int Ncols){
  int idx = blockIdx.x*256 + threadIdx.x;
  if (idx >= K*Ncols) return;
  int n = idx / K, k = idx - n*K;
  WT[idx] = __float2bfloat16(W[(size_t)k*Ncols + n]);
}

// ---------------- BN column stats (sum, sumsq) ----------------
__global__ void k_bnstats(const float* __restrict__ X, float* __restrict__ sums, int M, int C){
  int c = threadIdx.x;
  float s = 0.f, s2 = 0.f;
  for (int r = blockIdx.x; r < M; r += gridDim.x){
    float v = X[(size_t)r*C + c];
    s += v; s2 += v*v;
  }
  atomicAdd(&sums[c], s);
  atomicAdd(&sums[C+c], s2);
}

// ---------------- BN apply (mu/rsig computed inline) ----------------
__global__ void k_bnapply(const float* __restrict__ X, const float* __restrict__ sums,
                          const float* __restrict__ g, const float* __restrict__ b,
                          const float* __restrict__ addin, float* __restrict__ outf,
                          bf16* __restrict__ outb, int M, int Cm1, int relu){
  int idx = blockIdx.x*256 + threadIdx.x;
  int c = idx & Cm1;
  int C = Cm1 + 1;
  float mu = sums[c] / (float)M;
  float var = sums[C+c] / (float)M - mu*mu;
  float rs = rsqrtf(var + 1e-5f);
  float v = (X[idx] - mu)*rs*g[c] + b[c];
  if (addin) v += addin[idx];
  if (relu) v = fmaxf(v, 0.f);
  if (outf) outf[idx] = v;
  if (outb) outb[idx] = __float2bfloat16(v);
}

// ---------------- strip GEMM: C[M x Ncols] = A[M x K] @ BT^T, 1 wave = 16 rows ----------------
template<int KCH>
__global__ __launch_bounds__(64)
void k_gemm(const bf16* __restrict__ A, const bf16* __restrict__ BT,
            const float* __restrict__ bias, const float* __restrict__ resid,
            float* __restrict__ Cf, bf16* __restrict__ Cb,
            int Ncols, int ldc, int relu)
{
  constexpr int K = KCH*32;
  const int row0 = blockIdx.x*16;
  const int lane = threadIdx.x;
  const int lr = lane & 15, lg = lane >> 4;
  short8 af[KCH];
  const short* Arow = (const short*)A + (size_t)(row0+lr)*K + lg*8;
#pragma unroll
  for (int c2 = 0; c2 < KCH; c2++) af[c2] = *(const short8*)(Arow + c2*32);
  const int ntiles = Ncols >> 4;
  for (int ct = 0; ct < ntiles; ct++){
    f32x4 acc = {0.f,0.f,0.f,0.f};
    const short* Brow = (const short*)BT + (size_t)(ct*16+lr)*K + lg*8;
#pragma unroll
    for (int c2 = 0; c2 < KCH; c2++){
      short8 bfr = *(const short8*)(Brow + c2*32);
      acc = __builtin_amdgcn_mfma_f32_16x16x32_bf16(af[c2], bfr, acc, 0, 0, 0);
    }
    int col = ct*16 + lr;
    float bvv = bias ? bias[col] : 0.f;
#pragma unroll
    for (int r = 0; r < 4; r++){
      int row = row0 + lg*4 + r;
      size_t o = (size_t)row*ldc + col;
      float v = acc[r] + bvv;
      if (resid) v += resid[o];
      if (relu) v = fmaxf(v, 0.f);
      if (Cf) Cf[o] = v;
      if (Cb) Cb[o] = __float2bfloat16(v);
    }
  }
}

// ---------------- CSR build for gather-form GCN aggregation ----------------
__global__ void k_hist(const int* __restrict__ dst, int* __restrict__ cnt){
  int e = blockIdx.x*256 + threadIdx.x;
  if (e < EE) atomicAdd(&cnt[dst[e]], 1);
}

__global__ void k_scan(const int* __restrict__ cnt, int* __restrict__ off, int* __restrict__ woff){
  __shared__ int s[256];
  int t = threadIdx.x;
  int base = t*32;
  int local[32];
  int sum = 0;
#pragma unroll
  for (int i = 0; i < 32; i++){ local[i] = sum; sum += cnt[base+i]; }
  s[t] = sum;
  __syncthreads();
  if (t == 0){
    int run = 0;
    for (int i = 0; i < 256; i++){ int v = s[i]; s[i] = run; run += v; }
  }
  __syncthreads();
  int b = s[t];
#pragma unroll
  for (int i = 0; i < 32; i++){ off[base+i] = b + local[i]; woff[base+i] = b + local[i]; }
  if (t == 255) off[8192] = EE;
}

__global__ void k_fill(const int* __restrict__ dst, int* __restrict__ woff, int* __restrict__ elist){
  int e = blockIdx.x*256 + threadIdx.x;
  if (e < EE){
    int p = atomicAdd(&woff[dst[e]], 1);
    elist[p] = e;
  }
}

// deg/dinv per node from CSR (deg = sum of incoming ew, +1 self)
__global__ __launch_bounds__(256)
void k_degcsr(const int* __restrict__ off, const int* __restrict__ elist,
              const float* __restrict__ ew, float* __restrict__ dinv){
  int n = blockIdx.x*4 + (threadIdx.x >> 6);
  int lane = threadIdx.x & 63;
  int o0 = off[n], o1 = off[n+1];
  float s = 0.f;
  for (int j = o0 + lane; j < o1; j += 64) s += ew[elist[j]];
#pragma unroll
  for (int o = 32; o; o >>= 1) s += __shfl_xor(s, o, 64);
  if (lane == 0) dinv[n] = rsqrtf(s + 1.0f);
}

// gather aggregation, fused with y1 = agg + hw*dinv^2 + b_gcn + h
__global__ __launch_bounds__(256)
void k_gather(const int* __restrict__ off, const int* __restrict__ elist,
              const float* __restrict__ ew, const float* __restrict__ dinv,
              const float* __restrict__ hw, const float* __restrict__ h,
              const float* __restrict__ bgcn, float* __restrict__ y1){
  int n = blockIdx.x*4 + (threadIdx.x >> 6);
  int lane = threadIdx.x & 63;
  int o0 = off[n], o1 = off[n+1];
  float dn = dinv[n];
  f32x4 acc = {0.f,0.f,0.f,0.f};
  for (int j = o0; j < o1; j++){
    int e = elist[j];
    int s = e >> 5;                 // src[e] = e/32 by construction
    float coef = dinv[s]*ew[e]*dn;
    f32x4 v = ((const f32x4*)(hw + (size_t)s*CH))[lane];
    acc[0] += v[0]*coef; acc[1] += v[1]*coef;
    acc[2] += v[2]*coef; acc[3] += v[3]*coef;
  }
  f32x4 hwn = ((const f32x4*)(hw + (size_t)n*CH))[lane];
  f32x4 hn  = ((const f32x4*)(h  + (size_t)n*CH))[lane];
  f32x4 bg  = ((const f32x4*)bgcn)[lane];
  float dd = dn*dn;
  f32x4 o;
  o[0] = acc[0] + hwn[0]*dd + bg[0] + hn[0];
  o[1] = acc[1] + hwn[1]*dd + bg[1] + hn[1];
  o[2] = acc[2] + hwn[2]*dd + bg[2] + hn[2];
  o[3] = acc[3] + hwn[3]*dd + bg[3] + hn[3];
  ((f32x4*)(y1 + (size_t)n*CH))[lane] = o;
}

// ---------------- bf16 transpose 8192x256 -> 256x8192 ----------------
__global__ __launch_bounds__(256)
void k_transpose(const bf16* __restrict__ in, bf16* __restrict__ out){
  __shared__ short tile[32][33];
  int bx = blockIdx.x & 7;        // col tile (256/32)
  int by = blockIdx.x >> 3;       // row tile (8192/32)
  int tx = threadIdx.x & 31, ty = threadIdx.x >> 5;
  const short* inp = (const short*)in;
  short* outp = (short*)out;
#pragma unroll
  for (int i = 0; i < 4; i++)
    tile[ty + i*8][tx] = inp[(size_t)(by*32 + ty + i*8)*256 + bx*32 + tx];
  __syncthreads();
#pragma unroll
  for (int i = 0; i < 4; i++)
    outp[(size_t)(bx*32 + ty + i*8)*8192 + by*32 + tx] = tile[tx][ty + i*8];
}

// ---------------- flash attention: 4 waves x 16 queries, 2 key-splits ----------------
__global__ __launch_bounds__(256)
void k_attn(const bf16* __restrict__ Qm, const bf16* __restrict__ Km, const bf16* __restrict__ VT,
            float* __restrict__ Opart, float* __restrict__ Mpart, float* __restrict__ Lpart)
{
  __shared__ short sP[4][16*32];
  const int wid = threadIdx.x >> 6, lane = threadIdx.x & 63;
  const int lr = lane & 15, lg = lane >> 4;
  const int qblock = blockIdx.x >> 1, split = blockIdx.x & 1;
  const int q0 = qblock*64 + wid*16;
  const int k0base = split*4096;

  short8 qf[8];
  const short* Qrow = (const short*)Qm + (size_t)(q0+lr)*CH + lg*8;
#pragma unroll
  for (int c = 0; c < 8; c++) qf[c] = *(const short8*)(Qrow + c*32);

  f32x4 acc[16];
#pragma unroll
  for (int dt = 0; dt < 16; dt++) acc[dt] = {0.f,0.f,0.f,0.f};
  float m[4], lsum[4];
#pragma unroll
  for (int r = 0; r < 4; r++){ m[r] = -1e30f; lsum[r] = 0.f; }
  const float scale = 0.0625f; // 1/sqrt(256)

  for (int kt = 0; kt < 128; kt++){
    const int k0 = k0base + kt*32;
    f32x4 s0 = {0.f,0.f,0.f,0.f}, s1 = {0.f,0.f,0.f,0.f};
    const short* Krow0 = (const short*)Km + (size_t)(k0+lr)*CH + lg*8;
    const short* Krow1 = Krow0 + 16*CH;
#pragma unroll
    for (int c = 0; c < 8; c++){
      short8 kf0 = *(const short8*)(Krow0 + c*32);
      s0 = __builtin_amdgcn_mfma_f32_16x16x32_bf16(qf[c], kf0, s0, 0, 0, 0);
      short8 kf1 = *(const short8*)(Krow1 + c*32);
      s1 = __builtin_amdgcn_mfma_f32_16x16x32_bf16(qf[c], kf1, s1, 0, 0, 0);
    }
    // online softmax over these 32 keys; lane holds rows lg*4+r, key col lr / 16+lr
#pragma unroll
    for (int r = 0; r < 4; r++){
      float x0 = s0[r]*scale, x1 = s1[r]*scale;
      float pm = fmaxf(x0, x1);
#pragma unroll
      for (int off = 1; off < 16; off <<= 1) pm = fmaxf(pm, __shfl_xor(pm, off, 64));
      float mn = fmaxf(m[r], pm);
      float al = __expf(m[r] - mn);
      float p0 = __expf(x0 - mn), p1 = __expf(x1 - mn);
      float rsm = p0 + p1;
#pragma unroll
      for (int off = 1; off < 16; off <<= 1) rsm += __shfl_xor(rsm, off, 64);
      lsum[r] = lsum[r]*al + rsm;
      m[r] = mn;
#pragma unroll
      for (int dt = 0; dt < 16; dt++) acc[dt][r] *= al;
      int prow = lg*4 + r;
      sP[wid][prow*32 + lr]      = f2bf(p0);
      sP[wid][prow*32 + 16 + lr] = f2bf(p1);
    }
    __builtin_amdgcn_sched_barrier(0);
    // re-layout P into A-frag: row = lr (query), k = lg*8.. (key)
    short8 pf = *(const short8*)(&sP[wid][lr*32 + lg*8]);
    // PV: O += P @ V ; B-frag from VT rows (dims), contiguous keys
#pragma unroll
    for (int dt = 0; dt < 16; dt++){
      const short* Vrow = (const short*)VT + (size_t)(dt*16 + lr)*8192 + k0 + lg*8;
      short8 vf = *(const short8*)Vrow;
      acc[dt] = __builtin_amdgcn_mfma_f32_16x16x32_bf16(pf, vf, acc[dt], 0, 0, 0);
    }
  }
  size_t base = (size_t)split*NN*CH;
#pragma unroll
  for (int dt = 0; dt < 16; dt++){
#pragma unroll
    for (int r = 0; r < 4; r++){
      int row = q0 + lg*4 + r;
      Opart[base + (size_t)row*CH + dt*16 + lr] = acc[dt][r];
    }
  }
  if (lr == 0){
#pragma unroll
    for (int r = 0; r < 4; r++){
      int row = q0 + lg*4 + r;
      Mpart[split*NN + row] = m[r];
      Lpart[split*NN + row] = lsum[r];
    }
  }
}

__global__ void k_merge(const float* __restrict__ Opart, const float* __restrict__ Mp,
                        const float* __restrict__ Lp, bf16* __restrict__ out){
  int idx = blockIdx.x*256 + threadIdx.x;   // over NN*CH
  int q = idx >> 8;
  float m0 = Mp[q], m1 = Mp[NN+q], l0 = Lp[q], l1 = Lp[NN+q];
  float M = fmaxf(m0, m1);
  float w0 = __expf(m0 - M), w1 = __expf(m1 - M);
  float denom = l0*w0 + l1*w1;
  float v = (Opart[idx]*w0 + Opart[(size_t)NN*CH + idx]*w1) / denom;
  out[idx] = __float2bfloat16(v);
}

// ---------------- link-prediction head ----------------
__global__ void k_content(const int* __restrict__ eli, const float* __restrict__ z3, bf16* __restrict__ outc){
  int idx = blockIdx.x*256 + threadIdx.x;   // over QQ*CH
  int q = idx >> 8, c = idx & 255;
  int a = eli[q], b = eli[QQ + q];
  outc[idx] = __float2bfloat16(z3[(size_t)a*CH + c]*z3[(size_t)b*CH + c]);
}

__global__ __launch_bounds__(256)
void k_structure(const int* __restrict__ eli, const int* __restrict__ nbr,
                 const float* __restrict__ z3, const float* __restrict__ tptr, bf16* __restrict__ outs){
  __shared__ int tn[32];
  __shared__ int msk[32];
  int q = blockIdx.x;
  if (threadIdx.x < 32){
    int d = threadIdx.x;
    int a = nbr[(size_t)eli[q]*DD + d];       // t_nbr (neighbors of eli0)
    int s = nbr[(size_t)eli[QQ+q]*DD + d];    // s_nbr (neighbors of eli1)
    tn[d] = a;
    msk[d] = (a == s);
  }
  __syncthreads();
  int c = threadIdx.x;
  float tval = tptr[0];
  float vmax = -1e30f;
  float zg[32];
#pragma unroll
  for (int d = 0; d < 32; d++){
    float v = msk[d] ? z3[(size_t)tn[d]*CH + c] : 0.f;
    zg[d] = v;
    float sc = msk[d] ? tval*v : -1e30f;
    vmax = fmaxf(vmax, sc);
  }
  float esum = 0.f, wsum = 0.f;
#pragma unroll
  for (int d = 0; d < 32; d++){
    float e = msk[d] ? __expf(tval*zg[d] - vmax) : 0.f;
    esum += e;
    wsum += e*zg[d];
  }
  outs[(size_t)q*CH + c] = __float2bfloat16(wsum / fmaxf(esum, 1e-12f));
}

__global__ __launch_bounds__(256)
void k_final(const bf16* __restrict__ hmid, const float* __restrict__ w,
             const float* __restrict__ b, float* __restrict__ out){
  int r = blockIdx.x*4 + (threadIdx.x >> 6);
  int lane = threadIdx.x & 63;
  float s = 0.f;
#pragma unroll
  for (int i = 0; i < 4; i++){
    int c = lane + 64*i;
    s += __bfloat162float(hmid[(size_t)r*CH + c]) * w[c];
  }
#pragma unroll
  for (int off = 32; off; off >>= 1) s += __shfl_xor(s, off, 64);
  if (lane == 0) out[r] = s + b[0];
}

// =====================================================================
extern "C" void kernel_launch(void* const* d_in, const int* in_sizes, int n_in,
                              void* d_out, int out_size, void* d_ws, size_t ws_size,
                              hipStream_t stream)
{
  const float* x      = (const float*)d_in[0];
  const int*   eidx   = (const int*)d_in[1];
  const float* ew     = (const float*)d_in[2];
  const int*   eli    = (const int*)d_in[3];
  const int*   nbr    = (const int*)d_in[4];
  const float* pe_g   = (const float*)d_in[5];
  const float* pe_b   = (const float*)d_in[6];
  const float* W_pe   = (const float*)d_in[7];
  const float* b_pe   = (const float*)d_in[8];
  const float* W_gcn  = (const float*)d_in[9];
  const float* b_gcn  = (const float*)d_in[10];
  const float* bn1_g  = (const float*)d_in[11];
  const float* bn1_b  = (const float*)d_in[12];
  const float* Wq     = (const float*)d_in[13];
  const float* bq     = (const float*)d_in[14];
  const float* Wk     = (const float*)d_in[15];
  const float* bk     = (const float*)d_in[16];
  const float* Wv     = (const float*)d_in[17];
  const float* bvv    = (const float*)d_in[18];
  const float* Wo     = (const float*)d_in[19];
  const float* bo     = (const float*)d_in[20];
  const float* bn2_g  = (const float*)d_in[21];
  const float* bn2_b  = (const float*)d_in[22];
  const float* W_m1   = (const float*)d_in[23];
  const float* b_m1   = (const float*)d_in[24];
  const float* W_m2   = (const float*)d_in[25];
  const float* b_m2   = (const float*)d_in[26];
  const float* bn3_g  = (const float*)d_in[27];
  const float* bn3_b  = (const float*)d_in[28];
  const float* W_cm   = (const float*)d_in[29];
  const float* b_cm   = (const float*)d_in[30];
  const float* W_sm   = (const float*)d_in[31];
  const float* b_sm   = (const float*)d_in[32];
  const float* W_o1   = (const float*)d_in[33];
  const float* b_o1   = (const float*)d_in[34];
  const float* bno_g  = (const float*)d_in[35];
  const float* bno_b  = (const float*)d_in[36];
  const float* W_o2   = (const float*)d_in[37];
  const float* b_o2   = (const float*)d_in[38];
  const float* tptr   = (const float*)d_in[39];

  if (ws_size < 64*MBYTE) return;
  char* ws = (char*)d_ws;

  // weights (bf16, transposed) at [0, 1.75MB)
  bf16* WpeT  = (bf16*)(ws + 0);
  bf16* WgcnT = (bf16*)(ws + 64*1024);
  bf16* WqT   = (bf16*)(ws + 192*1024);
  bf16* WkT   = (bf16*)(ws + 320*1024);
  bf16* WvT   = (bf16*)(ws + 448*1024);
  bf16* WoT   = (bf16*)(ws + 576*1024);
  bf16* Wm1T  = (bf16*)(ws + 704*1024);
  bf16* Wm2T  = (bf16*)(ws + 960*1024);
  bf16* WcmT  = (bf16*)(ws + 1216*1024);
  bf16* WsmT  = (bf16*)(ws + 1344*1024);
  bf16* Wo1T  = (bf16*)(ws + 1472*1024);
  // small region at 2MB
  float* stat_x = (float*)(ws + 2*MBYTE);
  float* stat1  = (float*)(ws + 2*MBYTE + 1024);
  float* stat2  = (float*)(ws + 2*MBYTE + 3*1024);
  float* stat3  = (float*)(ws + 2*MBYTE + 5*1024);
  float* stato  = (float*)(ws + 2*MBYTE + 7*1024);
  float* deg    = (float*)(ws + 2*MBYTE + 16*1024);   // dinv
  float* Mpart  = (float*)(ws + 2*MBYTE + 64*1024);
  float* Lpart  = (float*)(ws + 2*MBYTE + 128*1024);
  // big buffers (with manual lifetime reuse)
  bf16*  xn    = (bf16*)(ws + 4*MBYTE);     // 2MB; later: content
  float* hbuf  = (float*)(ws + 8*MBYTE);    // 8MB; later y2 in-place; later z3b+structure
  bf16*  hb    = (bf16*)(ws + 16*MBYTE);    // 4MB; later attn_bf16; later hcat
  float* hw    = (float*)(ws + 20*MBYTE);   // 8MB; later Opart[0]; later y3
  float* aggb  = (float*)(ws + 28*MBYTE);   // 8MB (y1); later Opart[1]; later z3
  float* h1    = (float*)(ws + 36*MBYTE);   // 8MB; later y4 + hmid
  bf16*  qb    = (bf16*)(ws + 44*MBYTE);    // 4MB; later z_f32 (8MB over q,k)
  bf16*  kb    = (bf16*)(ws + 48*MBYTE);
  bf16*  vb    = (bf16*)(ws + 52*MBYTE);    // later z_bf16
  bf16*  vT    = (bf16*)(ws + 56*MBYTE);    // later mid (8MB)
  float* Opart = (float*)(ws + 20*MBYTE);
  bf16*  attnb = (bf16*)(ws + 16*MBYTE);
  float* y2    = hbuf;
  float* zf    = (float*)(ws + 44*MBYTE);
  bf16*  zb    = (bf16*)(ws + 52*MBYTE);
  bf16*  midb  = (bf16*)(ws + 56*MBYTE);
  float* y3    = (float*)(ws + 20*MBYTE);
  float* z3    = (float*)(ws + 28*MBYTE);
  bf16*  z3b   = (bf16*)(ws + 8*MBYTE);
  bf16*  contb = (bf16*)(ws + 4*MBYTE);
  bf16*  strub = (bf16*)(ws + 12*MBYTE);
  bf16*  hcat  = (bf16*)(ws + 16*MBYTE);
  float* y4    = (float*)(ws + 36*MBYTE);
  bf16*  hmid  = (bf16*)(ws + 40*MBYTE);

  // CSR scratch lives in [44MB, 45.2MB) — dead before qb is written
  int* cnt   = (int*)(ws + 44*MBYTE);              // 32KB
  int* off   = (int*)(ws + 44*MBYTE + 32*1024);    // 8193 ints
  int* woff  = (int*)(ws + 44*MBYTE + 96*1024);    // 32KB
  int* elist = (int*)(ws + 44*MBYTE + 128*1024);   // 1MB

  const int* srcp = eidx;
  const int* dstp = eidx + EE;
  (void)srcp;

  // zero stats (48KB of floats) and CSR counters
  k_zero<<<(12288 + 8192 + 255)/256, 256, 0, stream>>>((float*)(ws + 2*MBYTE), 12288, (float*)cnt, 8192);

  // weight prep
  k_wconv<<<128, 256, 0, stream>>>(W_pe, WpeT, 128, 256);
  k_wconv<<<256, 256, 0, stream>>>(W_gcn, WgcnT, 256, 256);
  k_wconv<<<256, 256, 0, stream>>>(Wq, WqT, 256, 256);
  k_wconv<<<256, 256, 0, stream>>>(Wk, WkT, 256, 256);
  k_wconv<<<256, 256, 0, stream>>>(Wv, WvT, 256, 256);
  k_wconv<<<256, 256, 0, stream>>>(Wo, WoT, 256, 256);
  k_wconv<<<512, 256, 0, stream>>>(W_m1, Wm1T, 256, 512);
  k_wconv<<<512, 256, 0, stream>>>(W_m2, Wm2T, 512, 256);
  k_wconv<<<256, 256, 0, stream>>>(W_cm, WcmT, 256, 256);
  k_wconv<<<256, 256, 0, stream>>>(W_sm, WsmT, 256, 256);
  k_wconv<<<512, 256, 0, stream>>>(W_o1, Wo1T, 512, 256);

  // CSR build
  k_hist<<<EE/256, 256, 0, stream>>>(dstp, cnt);
  k_scan<<<1, 256, 0, stream>>>(cnt, off, woff);
  k_fill<<<EE/256, 256, 0, stream>>>(dstp, woff, elist);
  k_degcsr<<<NN/4, 256, 0, stream>>>(off, elist, ew, deg);

  // input BN -> xn (bf16)
  k_bnstats<<<256, 128, 0, stream>>>(x, stat_x, NN, CINN);
  k_bnapply<<<NN*CINN/256, 256, 0, stream>>>(x, stat_x, pe_g, pe_b, nullptr, nullptr, xn, NN, CINN-1, 0);

  // h = xn @ W_pe + b_pe  (f32 + bf16)
  k_gemm<4><<<NN/16, 64, 0, stream>>>(xn, WpeT, b_pe, nullptr, hbuf, hb, 256, 256, 0);

  // hw = h @ W_gcn
  k_gemm<8><<<NN/16, 64, 0, stream>>>(hb, WgcnT, nullptr, nullptr, hw, nullptr, 256, 256, 0);

  // gather aggregation fused with y1 = agg + hw*dinv^2 + b_gcn + h
  k_gather<<<NN/4, 256, 0, stream>>>(off, elist, ew, deg, hw, hbuf, b_gcn, aggb);

  // bn1 -> h1
  k_bnstats<<<256, 256, 0, stream>>>(aggb, stat1, NN, CH);
  k_bnapply<<<NN*CH/256, 256, 0, stream>>>(aggb, stat1, bn1_g, bn1_b, nullptr, h1, nullptr, NN, CH-1, 0);

  // q, k, v (bf16)
  k_gemm<8><<<NN/16, 64, 0, stream>>>(hb, WqT, bq, nullptr, nullptr, qb, 256, 256, 0);
  k_gemm<8><<<NN/16, 64, 0, stream>>>(hb, WkT, bk, nullptr, nullptr, kb, 256, 256, 0);
  k_gemm<8><<<NN/16, 64, 0, stream>>>(hb, WvT, bvv, nullptr, nullptr, vb, 256, 256, 0);
  k_transpose<<<2048, 256, 0, stream>>>(vb, vT);

  // attention (2 key-splits) + merge
  k_attn<<<256, 256, 0, stream>>>(qb, kb, vT, Opart, Mpart, Lpart);
  k_merge<<<NN*CH/256, 256, 0, stream>>>(Opart, Mpart, Lpart, attnb);

  // y2 = attn @ Wo + bo + h  (in-place over h)
  k_gemm<8><<<NN/16, 64, 0, stream>>>(attnb, WoT, bo, hbuf, hbuf, nullptr, 256, 256, 0);

  // z = h1 + bn2(y2)
  k_bnstats<<<256, 256, 0, stream>>>(y2, stat2, NN, CH);
  k_bnapply<<<NN*CH/256, 256, 0, stream>>>(y2, stat2, bn2_g, bn2_b, h1, zf, zb, NN, CH-1, 0);

  // mid = relu(z @ W_m1 + b_m1) (bf16), y3 = mid @ W_m2 + b_m2 + z
  k_gemm<8><<<NN/16, 64, 0, stream>>>(zb, Wm1T, b_m1, nullptr, nullptr, midb, 512, 512, 1);
  k_gemm<16><<<NN/16, 64, 0, stream>>>(midb, Wm2T, b_m2, zf, y3, nullptr, 256, 256, 0);

  // bn3 -> z3 (f32 + bf16)
  k_bnstats<<<256, 256, 0, stream>>>(y3, stat3, NN, CH);
  k_bnapply<<<NN*CH/256, 256, 0, stream>>>(y3, stat3, bn3_g, bn3_b, nullptr, z3, z3b, NN, CH-1, 0);

  // head: content & structure
  k_content<<<QQ*CH/256, 256, 0, stream>>>(eli, z3, contb);
  k_structure<<<QQ, 256, 0, stream>>>(eli, nbr, z3, tptr, strub);

  // hcat = [content@W_cm + b_cm | structure@W_sm + b_sm]  (bf16, ld=512)
  k_gemm<8><<<QQ/16, 64, 0, stream>>>(contb, WcmT, b_cm, nullptr, nullptr, hcat, 256, 512, 0);
  k_gemm<8><<<QQ/16, 64, 0, stream>>>(strub, WsmT, b_sm, nullptr, nullptr, hcat + 256, 256, 512, 0);

  // y4 = hcat @ W_o1 + b_o1 ; hmid = relu(bn_o(y4)) (bf16)
  k_gemm<16><<<QQ/16, 64, 0, stream>>>(hcat, Wo1T, b_o1, nullptr, y4, nullptr, 256, 256, 0);
  k_bnstats<<<256, 256, 0, stream>>>(y4, stato, QQ, CH);
  k_bnapply<<<QQ*CH/256, 256, 0, stream>>>(y4, stato, bno_g, bno_b, nullptr, nullptr, hmid, QQ, CH-1, 1);

  // out = hmid @ W_o2 + b_o2
  k_final<<<QQ/4, 256, 0, stream>>>(hmid, W_o2, b_o2, (float*)d_out);
}

// Round 3
// 840.525 us; speedup vs baseline: 2.2622x; 1.2786x over previous
//
#include <hip/hip_runtime.h>
#include <hip/hip_bf16.h>

using bf16 = __hip_bfloat16;
typedef __attribute__((ext_vector_type(8))) short short8;
typedef __attribute__((ext_vector_type(4))) float f32x4;

#define NN 8192
#define DD 32
#define QQ 4096
#define CINN 128
#define CH 256
#define EE (NN*DD)
#define MBYTE ((size_t)1024*1024)

__device__ __forceinline__ short f2bf(float f){
  bf16 h = __float2bfloat16(f);
  return *reinterpret_cast<short*>(&h);
}
__device__ __forceinline__ float bf2f(short s){
  unsigned int u = ((unsigned int)(unsigned short)s) << 16;
  return __uint_as_float(u);
}

// ---------------- zero scratch ----------------
__global__ void k_zero(float* p1, int n1, float* p2, int n2){
  int i = blockIdx.x*256 + threadIdx.x;
  if (i < n1) p1[i] = 0.f;
  else if (i < n1 + n2) p2[i - n1] = 0.f;
}

// ---------------- weight convert+transpose: W (K x N f32) -> WT (N x K bf16), optional scale ----------------
__global__ void k_wconv(const float* __restrict__ W, bf16* __restrict__ WT, int K, int Ncols, float scale){
  int idx = blockIdx.x*256 + threadIdx.x;
  if (idx >= K*Ncols) return;
  int n = idx / K, k = idx - n*K;
  WT[idx] = __float2bfloat16(W[(size_t)k*Ncols + n] * scale);
}

// ---------------- BN column stats (sum, sumsq) ----------------
__global__ void k_bnstats(const float* __restrict__ X, float* __restrict__ sums, int M, int C){
  int c = threadIdx.x;
  float s = 0.f, s2 = 0.f;
  for (int r = blockIdx.x; r < M; r += gridDim.x){
    float v = X[(size_t)r*C + c];
    s += v; s2 += v*v;
  }
  atomicAdd(&sums[c], s);
  atomicAdd(&sums[C+c], s2);
}

// ---------------- BN apply (mu/rsig computed inline) ----------------
__global__ void k_bnapply(const float* __restrict__ X, const float* __restrict__ sums,
                          const float* __restrict__ g, const float* __restrict__ b,
                          const float* __restrict__ addin, float* __restrict__ outf,
                          bf16* __restrict__ outb, int M, int Cm1, int relu){
  int idx = blockIdx.x*256 + threadIdx.x;
  int c = idx & Cm1;
  int C = Cm1 + 1;
  float mu = sums[c] / (float)M;
  float var = sums[C+c] / (float)M - mu*mu;
  float rs = rsqrtf(var + 1e-5f);
  float v = (X[idx] - mu)*rs*g[c] + b[c];
  if (addin) v += addin[idx];
  if (relu) v = fmaxf(v, 0.f);
  if (outf) outf[idx] = v;
  if (outb) outb[idx] = __float2bfloat16(v);
}

// ---------------- strip GEMM: 4 waves/block, wave w does col tiles w, w+4, ... ----------------
template<int KCH>
__global__ __launch_bounds__(256)
void k_gemm(const bf16* __restrict__ A, const bf16* __restrict__ BT,
            const float* __restrict__ bias, const float* __restrict__ resid,
            float* __restrict__ Cf, bf16* __restrict__ Cb,
            int Ncols, int ldc, int relu, float bscale)
{
  constexpr int K = KCH*32;
  const int row0 = blockIdx.x*16;
  const int wid = threadIdx.x >> 6;
  const int lane = threadIdx.x & 63;
  const int lr = lane & 15, lg = lane >> 4;
  short8 af[KCH];
  const short* Arow = (const short*)A + (size_t)(row0+lr)*K + lg*8;
#pragma unroll
  for (int c2 = 0; c2 < KCH; c2++) af[c2] = *(const short8*)(Arow + c2*32);
  const int ntiles = Ncols >> 4;
  for (int ct = wid; ct < ntiles; ct += 4){
    f32x4 acc = {0.f,0.f,0.f,0.f};
    const short* Brow = (const short*)BT + (size_t)(ct*16+lr)*K + lg*8;
#pragma unroll
    for (int c2 = 0; c2 < KCH; c2++){
      short8 bfr = *(const short8*)(Brow + c2*32);
      acc = __builtin_amdgcn_mfma_f32_16x16x32_bf16(af[c2], bfr, acc, 0, 0, 0);
    }
    int col = ct*16 + lr;
    float bvv = bias ? bias[col]*bscale : 0.f;
#pragma unroll
    for (int r = 0; r < 4; r++){
      int row = row0 + lg*4 + r;
      size_t o = (size_t)row*ldc + col;
      float v = acc[r] + bvv;
      if (resid) v += resid[o];
      if (relu) v = fmaxf(v, 0.f);
      if (Cf) Cf[o] = v;
      if (Cb) Cb[o] = __float2bfloat16(v);
    }
  }
}

// ---------------- CSR build for gather-form GCN aggregation ----------------
__global__ void k_hist(const int* __restrict__ dst, int* __restrict__ cnt){
  int e = blockIdx.x*256 + threadIdx.x;
  if (e < EE) atomicAdd(&cnt[dst[e]], 1);
}

__global__ void k_scan(const int* __restrict__ cnt, int* __restrict__ off, int* __restrict__ woff){
  __shared__ int s[256];
  int t = threadIdx.x;
  int base = t*32;
  int local[32];
  int sum = 0;
#pragma unroll
  for (int i = 0; i < 32; i++){ local[i] = sum; sum += cnt[base+i]; }
  s[t] = sum;
  __syncthreads();
  if (t == 0){
    int run = 0;
    for (int i = 0; i < 256; i++){ int v = s[i]; s[i] = run; run += v; }
  }
  __syncthreads();
  int b = s[t];
#pragma unroll
  for (int i = 0; i < 32; i++){ off[base+i] = b + local[i]; woff[base+i] = b + local[i]; }
  if (t == 255) off[8192] = EE;
}

__global__ void k_fill(const int* __restrict__ dst, int* __restrict__ woff, int* __restrict__ elist){
  int e = blockIdx.x*256 + threadIdx.x;
  if (e < EE){
    int p = atomicAdd(&woff[dst[e]], 1);
    elist[p] = e;
  }
}

__global__ __launch_bounds__(256)
void k_degcsr(const int* __restrict__ off, const int* __restrict__ elist,
              const float* __restrict__ ew, float* __restrict__ dinv){
  int n = blockIdx.x*4 + (threadIdx.x >> 6);
  int lane = threadIdx.x & 63;
  int o0 = off[n], o1 = off[n+1];
  float s = 0.f;
  for (int j = o0 + lane; j < o1; j += 64) s += ew[elist[j]];
#pragma unroll
  for (int o = 32; o; o >>= 1) s += __shfl_xor(s, o, 64);
  if (lane == 0) dinv[n] = rsqrtf(s + 1.0f);
}

// gather aggregation, fused with y1 = agg + hw*dinv^2 + b_gcn + h
__global__ __launch_bounds__(256)
void k_gather(const int* __restrict__ off, const int* __restrict__ elist,
              const float* __restrict__ ew, const float* __restrict__ dinv,
              const float* __restrict__ hw, const float* __restrict__ h,
              const float* __restrict__ bgcn, float* __restrict__ y1){
  int n = blockIdx.x*4 + (threadIdx.x >> 6);
  int lane = threadIdx.x & 63;
  int o0 = off[n], o1 = off[n+1];
  float dn = dinv[n];
  f32x4 acc = {0.f,0.f,0.f,0.f};
  for (int j = o0; j < o1; j++){
    int e = elist[j];
    int s = e >> 5;                 // src[e] = e/32 by construction
    float coef = dinv[s]*ew[e]*dn;
    f32x4 v = ((const f32x4*)(hw + (size_t)s*CH))[lane];
    acc[0] += v[0]*coef; acc[1] += v[1]*coef;
    acc[2] += v[2]*coef; acc[3] += v[3]*coef;
  }
  f32x4 hwn = ((const f32x4*)(hw + (size_t)n*CH))[lane];
  f32x4 hn  = ((const f32x4*)(h  + (size_t)n*CH))[lane];
  f32x4 bg  = ((const f32x4*)bgcn)[lane];
  float dd = dn*dn;
  f32x4 o;
  o[0] = acc[0] + hwn[0]*dd + bg[0] + hn[0];
  o[1] = acc[1] + hwn[1]*dd + bg[1] + hn[1];
  o[2] = acc[2] + hwn[2]*dd + bg[2] + hn[2];
  o[3] = acc[3] + hwn[3]*dd + bg[3] + hn[3];
  ((f32x4*)(y1 + (size_t)n*CH))[lane] = o;
}

// ---------------- bf16 transpose 8192x256 -> 256x8192 ----------------
__global__ __launch_bounds__(256)
void k_transpose(const bf16* __restrict__ in, bf16* __restrict__ out){
  __shared__ short tile[32][33];
  int bx = blockIdx.x & 7;
  int by = blockIdx.x >> 3;
  int tx = threadIdx.x & 31, ty = threadIdx.x >> 5;
  const short* inp = (const short*)in;
  short* outp = (short*)out;
#pragma unroll
  for (int i = 0; i < 4; i++)
    tile[ty + i*8][tx] = inp[(size_t)(by*32 + ty + i*8)*256 + bx*32 + tx];
  __syncthreads();
#pragma unroll
  for (int i = 0; i < 4; i++)
    outp[(size_t)(bx*32 + ty + i*8)*8192 + by*32 + tx] = tile[tx][ty + i*8];
}

// ---------------- flash attention: 8 waves = 8 key-splits of one 16-query tile ----------------
// Q pre-scaled by 1/16 (folded into Wq/bq). In-block split merge via LDS.
__global__ __launch_bounds__(512, 4)
void k_attn(const bf16* __restrict__ Qm, const bf16* __restrict__ Km, const bf16* __restrict__ VT,
            bf16* __restrict__ out)
{
  __shared__ short sO[8][16][256];   // 64KB bf16 partial O per wave
  __shared__ float sM[8][16];
  __shared__ float sL[8][16];
  __shared__ short sP[8][512];       // 8KB P re-layout buffer
  const int wid = threadIdx.x >> 6, lane = threadIdx.x & 63;
  const int lr = lane & 15, lg = lane >> 4;
  const int q0 = blockIdx.x * 16;
  const int k0base = wid * 1024;

  short8 qf[8];
  const short* Qrow = (const short*)Qm + (size_t)(q0+lr)*CH + lg*8;
#pragma unroll
  for (int c = 0; c < 8; c++) qf[c] = *(const short8*)(Qrow + c*32);

  f32x4 acc[16];
#pragma unroll
  for (int dt = 0; dt < 16; dt++) acc[dt] = {0.f,0.f,0.f,0.f};
  float m[4], ls[4];
#pragma unroll
  for (int r = 0; r < 4; r++){ m[r] = -1e30f; ls[r] = 0.f; }

  for (int kt = 0; kt < 32; kt++){
    const int k0 = k0base + kt*32;
    f32x4 s0 = {0.f,0.f,0.f,0.f}, s1 = {0.f,0.f,0.f,0.f};
    const short* Krow0 = (const short*)Km + (size_t)(k0+lr)*CH + lg*8;
    const short* Krow1 = Krow0 + 16*CH;
#pragma unroll
    for (int c = 0; c < 8; c++){
      short8 kf0 = *(const short8*)(Krow0 + c*32);
      s0 = __builtin_amdgcn_mfma_f32_16x16x32_bf16(qf[c], kf0, s0, 0, 0, 0);
      short8 kf1 = *(const short8*)(Krow1 + c*32);
      s1 = __builtin_amdgcn_mfma_f32_16x16x32_bf16(qf[c], kf1, s1, 0, 0, 0);
    }
    // tile max per row; exact defer-rescale (skip acc mults when max unchanged)
    float pm[4];
    int need = 0;
#pragma unroll
    for (int r = 0; r < 4; r++){
      float p = fmaxf(s0[r], s1[r]);
#pragma unroll
      for (int off = 1; off < 16; off <<= 1) p = fmaxf(p, __shfl_xor(p, off, 64));
      pm[r] = p;
      need |= (p > m[r]) ? 1 : 0;
    }
    if (__any(need)){
#pragma unroll
      for (int r = 0; r < 4; r++){
        float mn = fmaxf(m[r], pm[r]);
        float al = __expf(m[r] - mn);
        m[r] = mn;
        ls[r] *= al;
#pragma unroll
        for (int dt = 0; dt < 16; dt++) acc[dt][r] *= al;
      }
    }
#pragma unroll
    for (int r = 0; r < 4; r++){
      float p0 = __expf(s0[r] - m[r]);
      float p1 = __expf(s1[r] - m[r]);
      ls[r] += p0 + p1;                 // per-lane partial sum; reduced once at end
      int prow = lg*4 + r;
      sP[wid][prow*32 + lr]      = f2bf(p0);
      sP[wid][prow*32 + 16 + lr] = f2bf(p1);
    }
    __builtin_amdgcn_sched_barrier(0);
    short8 pf = *(const short8*)(&sP[wid][lr*32 + lg*8]);
#pragma unroll
    for (int dt = 0; dt < 16; dt++){
      const short* Vrow = (const short*)VT + (size_t)(dt*16 + lr)*8192 + k0 + lg*8;
      short8 vf = *(const short8*)Vrow;
      acc[dt] = __builtin_amdgcn_mfma_f32_16x16x32_bf16(pf, vf, acc[dt], 0, 0, 0);
    }
  }
  // final 16-lane reduce of per-lane lsums
#pragma unroll
  for (int r = 0; r < 4; r++){
#pragma unroll
    for (int off = 1; off < 16; off <<= 1) ls[r] += __shfl_xor(ls[r], off, 64);
  }
  if (lr == 0){
#pragma unroll
    for (int r = 0; r < 4; r++){
      sM[wid][lg*4 + r] = m[r];
      sL[wid][lg*4 + r] = ls[r];
    }
  }
#pragma unroll
  for (int dt = 0; dt < 16; dt++){
#pragma unroll
    for (int r = 0; r < 4; r++)
      sO[wid][lg*4 + r][dt*16 + lr] = f2bf(acc[dt][r]);
  }
  __syncthreads();
  // merge: 512 threads over 16 rows x 32 chunks of 8 cols
  const int row = threadIdx.x >> 5;
  const int colb = (threadIdx.x & 31) * 8;
  float Mx = sM[0][row];
#pragma unroll
  for (int w = 1; w < 8; w++) Mx = fmaxf(Mx, sM[w][row]);
  float den = 0.f, wt[8];
#pragma unroll
  for (int w = 0; w < 8; w++){ wt[w] = __expf(sM[w][row] - Mx); den += sL[w][row]*wt[w]; }
  float inv = 1.f / den;
  float o[8];
#pragma unroll
  for (int j = 0; j < 8; j++) o[j] = 0.f;
#pragma unroll
  for (int w = 0; w < 8; w++){
    short8 v = *(const short8*)&sO[w][row][colb];
    float f = wt[w];
#pragma unroll
    for (int j = 0; j < 8; j++) o[j] += bf2f(v[j]) * f;
  }
  short8 res;
#pragma unroll
  for (int j = 0; j < 8; j++) res[j] = f2bf(o[j]*inv);
  *(short8*)((short*)out + (size_t)(q0+row)*CH + colb) = res;
}

// ---------------- link-prediction head ----------------
__global__ void k_content(const int* __restrict__ eli, const float* __restrict__ z3, bf16* __restrict__ outc){
  int idx = blockIdx.x*256 + threadIdx.x;
  int q = idx >> 8, c = idx & 255;
  int a = eli[q], b = eli[QQ + q];
  outc[idx] = __float2bfloat16(z3[(size_t)a*CH + c]*z3[(size_t)b*CH + c]);
}

__global__ __launch_bounds__(256)
void k_structure(const int* __restrict__ eli, const int* __restrict__ nbr,
                 const float* __restrict__ z3, const float* __restrict__ tptr, bf16* __restrict__ outs){
  __shared__ int tn[32];
  __shared__ int msk[32];
  int q = blockIdx.x;
  if (threadIdx.x < 32){
    int d = threadIdx.x;
    int a = nbr[(size_t)eli[q]*DD + d];
    int s = nbr[(size_t)eli[QQ+q]*DD + d];
    tn[d] = a;
    msk[d] = (a == s);
  }
  __syncthreads();
  int c = threadIdx.x;
  float tval = tptr[0];
  float vmax = -1e30f;
  float zg[32];
#pragma unroll
  for (int d = 0; d < 32; d++){
    float v = msk[d] ? z3[(size_t)tn[d]*CH + c] : 0.f;
    zg[d] = v;
    float sc = msk[d] ? tval*v : -1e30f;
    vmax = fmaxf(vmax, sc);
  }
  float esum = 0.f, wsum = 0.f;
#pragma unroll
  for (int d = 0; d < 32; d++){
    float e = msk[d] ? __expf(tval*zg[d] - vmax) : 0.f;
    esum += e;
    wsum += e*zg[d];
  }
  outs[(size_t)q*CH + c] = __float2bfloat16(wsum / fmaxf(esum, 1e-12f));
}

__global__ __launch_bounds__(256)
void k_final(const bf16* __restrict__ hmid, const float* __restrict__ w,
             const float* __restrict__ b, float* __restrict__ out){
  int r = blockIdx.x*4 + (threadIdx.x >> 6);
  int lane = threadIdx.x & 63;
  float s = 0.f;
#pragma unroll
  for (int i = 0; i < 4; i++){
    int c = lane + 64*i;
    s += __bfloat162float(hmid[(size_t)r*CH + c]) * w[c];
  }
#pragma unroll
  for (int off = 32; off; off >>= 1) s += __shfl_xor(s, off, 64);
  if (lane == 0) out[r] = s + b[0];
}

// =====================================================================
extern "C" void kernel_launch(void* const* d_in, const int* in_sizes, int n_in,
                              void* d_out, int out_size, void* d_ws, size_t ws_size,
                              hipStream_t stream)
{
  const float* x      = (const float*)d_in[0];
  const int*   eidx   = (const int*)d_in[1];
  const float* ew     = (const float*)d_in[2];
  const int*   eli    = (const int*)d_in[3];
  const int*   nbr    = (const int*)d_in[4];
  const float* pe_g   = (const float*)d_in[5];
  const float* pe_b   = (const float*)d_in[6];
  const float* W_pe   = (const float*)d_in[7];
  const float* b_pe   = (const float*)d_in[8];
  const float* W_gcn  = (const float*)d_in[9];
  const float* b_gcn  = (const float*)d_in[10];
  const float* bn1_g  = (const float*)d_in[11];
  const float* bn1_b  = (const float*)d_in[12];
  const float* Wq     = (const float*)d_in[13];
  const float* bq     = (const float*)d_in[14];
  const float* Wk     = (const float*)d_in[15];
  const float* bk     = (const float*)d_in[16];
  const float* Wv     = (const float*)d_in[17];
  const float* bvv    = (const float*)d_in[18];
  const float* Wo     = (const float*)d_in[19];
  const float* bo     = (const float*)d_in[20];
  const float* bn2_g  = (const float*)d_in[21];
  const float* bn2_b  = (const float*)d_in[22];
  const float* W_m1   = (const float*)d_in[23];
  const float* b_m1   = (const float*)d_in[24];
  const float* W_m2   = (const float*)d_in[25];
  const float* b_m2   = (const float*)d_in[26];
  const float* bn3_g  = (const float*)d_in[27];
  const float* bn3_b  = (const float*)d_in[28];
  const float* W_cm   = (const float*)d_in[29];
  const float* b_cm   = (const float*)d_in[30];
  const float* W_sm   = (const float*)d_in[31];
  const float* b_sm   = (const float*)d_in[32];
  const float* W_o1   = (const float*)d_in[33];
  const float* b_o1   = (const float*)d_in[34];
  const float* bno_g  = (const float*)d_in[35];
  const float* bno_b  = (const float*)d_in[36];
  const float* W_o2   = (const float*)d_in[37];
  const float* b_o2   = (const float*)d_in[38];
  const float* tptr   = (const float*)d_in[39];

  if (ws_size < 64*MBYTE) return;
  char* ws = (char*)d_ws;

  bf16* WpeT  = (bf16*)(ws + 0);
  bf16* WgcnT = (bf16*)(ws + 64*1024);
  bf16* WqT   = (bf16*)(ws + 192*1024);
  bf16* WkT   = (bf16*)(ws + 320*1024);
  bf16* WvT   = (bf16*)(ws + 448*1024);
  bf16* WoT   = (bf16*)(ws + 576*1024);
  bf16* Wm1T  = (bf16*)(ws + 704*1024);
  bf16* Wm2T  = (bf16*)(ws + 960*1024);
  bf16* WcmT  = (bf16*)(ws + 1216*1024);
  bf16* WsmT  = (bf16*)(ws + 1344*1024);
  bf16* Wo1T  = (bf16*)(ws + 1472*1024);
  float* stat_x = (float*)(ws + 2*MBYTE);
  float* stat1  = (float*)(ws + 2*MBYTE + 1024);
  float* stat2  = (float*)(ws + 2*MBYTE + 3*1024);
  float* stat3  = (float*)(ws + 2*MBYTE + 5*1024);
  float* stato  = (float*)(ws + 2*MBYTE + 7*1024);
  float* deg    = (float*)(ws + 2*MBYTE + 16*1024);
  bf16*  xn    = (bf16*)(ws + 4*MBYTE);
  float* hbuf  = (float*)(ws + 8*MBYTE);
  bf16*  hb    = (bf16*)(ws + 16*MBYTE);
  float* hw    = (float*)(ws + 20*MBYTE);
  float* aggb  = (float*)(ws + 28*MBYTE);
  float* h1    = (float*)(ws + 36*MBYTE);
  bf16*  qb    = (bf16*)(ws + 44*MBYTE);
  bf16*  kb    = (bf16*)(ws + 48*MBYTE);
  bf16*  vb    = (bf16*)(ws + 52*MBYTE);
  bf16*  vT    = (bf16*)(ws + 56*MBYTE);
  bf16*  attnb = (bf16*)(ws + 16*MBYTE);
  float* y2    = hbuf;
  float* zf    = (float*)(ws + 44*MBYTE);
  bf16*  zb    = (bf16*)(ws + 52*MBYTE);
  bf16*  midb  = (bf16*)(ws + 56*MBYTE);
  float* y3    = (float*)(ws + 20*MBYTE);
  float* z3    = (float*)(ws + 28*MBYTE);
  bf16*  z3b   = (bf16*)(ws + 8*MBYTE);
  bf16*  contb = (bf16*)(ws + 4*MBYTE);
  bf16*  strub = (bf16*)(ws + 12*MBYTE);
  bf16*  hcat  = (bf16*)(ws + 16*MBYTE);
  float* y4    = (float*)(ws + 36*MBYTE);
  bf16*  hmid  = (bf16*)(ws + 40*MBYTE);

  int* cnt   = (int*)(ws + 44*MBYTE);
  int* off   = (int*)(ws + 44*MBYTE + 32*1024);
  int* woff  = (int*)(ws + 44*MBYTE + 96*1024);
  int* elist = (int*)(ws + 44*MBYTE + 128*1024);

  const int* dstp = eidx + EE;

  k_zero<<<(12288 + 8192 + 255)/256, 256, 0, stream>>>((float*)(ws + 2*MBYTE), 12288, (float*)cnt, 8192);

  // weight prep (Wq/bq pre-scaled by 1/sqrt(C)=1/16)
  k_wconv<<<128, 256, 0, stream>>>(W_pe, WpeT, 128, 256, 1.f);
  k_wconv<<<256, 256, 0, stream>>>(W_gcn, WgcnT, 256, 256, 1.f);
  k_wconv<<<256, 256, 0, stream>>>(Wq, WqT, 256, 256, 0.0625f);
  k_wconv<<<256, 256, 0, stream>>>(Wk, WkT, 256, 256, 1.f);
  k_wconv<<<256, 256, 0, stream>>>(Wv, WvT, 256, 256, 1.f);
  k_wconv<<<256, 256, 0, stream>>>(Wo, WoT, 256, 256, 1.f);
  k_wconv<<<512, 256, 0, stream>>>(W_m1, Wm1T, 256, 512, 1.f);
  k_wconv<<<512, 256, 0, stream>>>(W_m2, Wm2T, 512, 256, 1.f);
  k_wconv<<<256, 256, 0, stream>>>(W_cm, WcmT, 256, 256, 1.f);
  k_wconv<<<256, 256, 0, stream>>>(W_sm, WsmT, 256, 256, 1.f);
  k_wconv<<<512, 256, 0, stream>>>(W_o1, Wo1T, 512, 256, 1.f);

  // CSR build
  k_hist<<<EE/256, 256, 0, stream>>>(dstp, cnt);
  k_scan<<<1, 256, 0, stream>>>(cnt, off, woff);
  k_fill<<<EE/256, 256, 0, stream>>>(dstp, woff, elist);
  k_degcsr<<<NN/4, 256, 0, stream>>>(off, elist, ew, deg);

  // input BN -> xn (bf16)
  k_bnstats<<<256, 128, 0, stream>>>(x, stat_x, NN, CINN);
  k_bnapply<<<NN*CINN/256, 256, 0, stream>>>(x, stat_x, pe_g, pe_b, nullptr, nullptr, xn, NN, CINN-1, 0);

  // h = xn @ W_pe + b_pe
  k_gemm<4><<<NN/16, 256, 0, stream>>>(xn, WpeT, b_pe, nullptr, hbuf, hb, 256, 256, 0, 1.f);

  // hw = h @ W_gcn
  k_gemm<8><<<NN/16, 256, 0, stream>>>(hb, WgcnT, nullptr, nullptr, hw, nullptr, 256, 256, 0, 1.f);

  // gather aggregation fused with y1
  k_gather<<<NN/4, 256, 0, stream>>>(off, elist, ew, deg, hw, hbuf, b_gcn, aggb);

  // bn1 -> h1
  k_bnstats<<<256, 256, 0, stream>>>(aggb, stat1, NN, CH);
  k_bnapply<<<NN*CH/256, 256, 0, stream>>>(aggb, stat1, bn1_g, bn1_b, nullptr, h1, nullptr, NN, CH-1, 0);

  // q (pre-scaled), k, v
  k_gemm<8><<<NN/16, 256, 0, stream>>>(hb, WqT, bq, nullptr, nullptr, qb, 256, 256, 0, 0.0625f);
  k_gemm<8><<<NN/16, 256, 0, stream>>>(hb, WkT, bk, nullptr, nullptr, kb, 256, 256, 0, 1.f);
  k_gemm<8><<<NN/16, 256, 0, stream>>>(hb, WvT, bvv, nullptr, nullptr, vb, 256, 256, 0, 1.f);
  k_transpose<<<2048, 256, 0, stream>>>(vb, vT);

  // attention: in-block 8-way key-split + merge
  k_attn<<<NN/16, 512, 0, stream>>>(qb, kb, vT, attnb);

  // y2 = attn @ Wo + bo + h  (in-place over h)
  k_gemm<8><<<NN/16, 256, 0, stream>>>(attnb, WoT, bo, hbuf, hbuf, nullptr, 256, 256, 0, 1.f);

  // z = h1 + bn2(y2)
  k_bnstats<<<256, 256, 0, stream>>>(y2, stat2, NN, CH);
  k_bnapply<<<NN*CH/256, 256, 0, stream>>>(y2, stat2, bn2_g, bn2_b, h1, zf, zb, NN, CH-1, 0);

  // MLP
  k_gemm<8><<<NN/16, 256, 0, stream>>>(zb, Wm1T, b_m1, nullptr, nullptr, midb, 512, 512, 1, 1.f);
  k_gemm<16><<<NN/16, 256, 0, stream>>>(midb, Wm2T, b_m2, zf, y3, nullptr, 256, 256, 0, 1.f);

  // bn3 -> z3
  k_bnstats<<<256, 256, 0, stream>>>(y3, stat3, NN, CH);
  k_bnapply<<<NN*CH/256, 256, 0, stream>>>(y3, stat3, bn3_g, bn3_b, nullptr, z3, z3b, NN, CH-1, 0);

  // head
  k_content<<<QQ*CH/256, 256, 0, stream>>>(eli, z3, contb);
  k_structure<<<QQ, 256, 0, stream>>>(eli, nbr, z3, tptr, strub);

  k_gemm<8><<<QQ/16, 256, 0, stream>>>(contb, WcmT, b_cm, nullptr, nullptr, hcat, 256, 512, 0, 1.f);
  k_gemm<8><<<QQ/16, 256, 0, stream>>>(strub, WsmT, b_sm, nullptr, nullptr, hcat + 256, 256, 512, 0, 1.f);

  k_gemm<16><<<QQ/16, 256, 0, stream>>>(hcat, Wo1T, b_o1, nullptr, y4, nullptr, 256, 256, 0, 1.f);
  k_bnstats<<<256, 256, 0, stream>>>(y4, stato, QQ, CH);
  k_bnapply<<<QQ*CH/256, 256, 0, stream>>>(y4, stato, bno_g, bno_b, nullptr, nullptr, hmid, QQ, CH-1, 1);

  k_final<<<QQ/4, 256, 0, stream>>>(hmid, W_o2, b_o2, (float*)d_out);
}

// Round 4
// 506.173 us; speedup vs baseline: 3.7565x; 1.6605x over previous
//
#include <hip/hip_runtime.h>
#include <hip/hip_bf16.h>

using bf16 = __hip_bfloat16;
typedef __attribute__((ext_vector_type(8))) short short8;
typedef __attribute__((ext_vector_type(4))) float f32x4;

#define NN 8192
#define DD 32
#define QQ 4096
#define CINN 128
#define CH 256
#define EE (NN*DD)
#define MBYTE ((size_t)1024*1024)

__device__ __forceinline__ short f2bf(float f){
  bf16 h = __float2bfloat16(f);
  return *reinterpret_cast<short*>(&h);
}
__device__ __forceinline__ float bf2f(short s){
  unsigned int u = ((unsigned int)(unsigned short)s) << 16;
  return __uint_as_float(u);
}
__device__ __forceinline__ void gl_lds16(const void* g, void* l){
  __builtin_amdgcn_global_load_lds(
      (const __attribute__((address_space(1))) void*)g,
      (__attribute__((address_space(3))) void*)l, 16, 0, 0);
}

// ---------------- zero scratch ----------------
__global__ void k_zero(float* p1, int n1, float* p2, int n2){
  int i = blockIdx.x*256 + threadIdx.x;
  if (i < n1) p1[i] = 0.f;
  else if (i < n1 + n2) p2[i - n1] = 0.f;
}

// ---------------- weight convert+transpose: W (K x N f32) -> WT (N x K bf16), optional scale ----------------
__global__ void k_wconv(const float* __restrict__ W, bf16* __restrict__ WT, int K, int Ncols, float scale){
  int idx = blockIdx.x*256 + threadIdx.x;
  if (idx >= K*Ncols) return;
  int n = idx / K, k = idx - n*K;
  WT[idx] = __float2bfloat16(W[(size_t)k*Ncols + n] * scale);
}

// ---------------- BN column stats (sum, sumsq) ----------------
__global__ void k_bnstats(const float* __restrict__ X, float* __restrict__ sums, int M, int C){
  int c = threadIdx.x;
  float s = 0.f, s2 = 0.f;
  for (int r = blockIdx.x; r < M; r += gridDim.x){
    float v = X[(size_t)r*C + c];
    s += v; s2 += v*v;
  }
  atomicAdd(&sums[c], s);
  atomicAdd(&sums[C+c], s2);
}

// ---------------- BN apply ----------------
__global__ void k_bnapply(const float* __restrict__ X, const float* __restrict__ sums,
                          const float* __restrict__ g, const float* __restrict__ b,
                          const float* __restrict__ addin, float* __restrict__ outf,
                          bf16* __restrict__ outb, int M, int Cm1, int relu){
  int idx = blockIdx.x*256 + threadIdx.x;
  int c = idx & Cm1;
  int C = Cm1 + 1;
  float mu = sums[c] / (float)M;
  float var = sums[C+c] / (float)M - mu*mu;
  float rs = rsqrtf(var + 1e-5f);
  float v = (X[idx] - mu)*rs*g[c] + b[c];
  if (addin) v += addin[idx];
  if (relu) v = fmaxf(v, 0.f);
  if (outf) outf[idx] = v;
  if (outb) outb[idx] = __float2bfloat16(v);
}

// ---------------- strip GEMM: 4 waves/block ----------------
template<int KCH>
__global__ __launch_bounds__(256)
void k_gemm(const bf16* __restrict__ A, const bf16* __restrict__ BT,
            const float* __restrict__ bias, const float* __restrict__ resid,
            float* __restrict__ Cf, bf16* __restrict__ Cb,
            int Ncols, int ldc, int relu, float bscale)
{
  constexpr int K = KCH*32;
  const int row0 = blockIdx.x*16;
  const int wid = threadIdx.x >> 6;
  const int lane = threadIdx.x & 63;
  const int lr = lane & 15, lg = lane >> 4;
  short8 af[KCH];
  const short* Arow = (const short*)A + (size_t)(row0+lr)*K + lg*8;
#pragma unroll
  for (int c2 = 0; c2 < KCH; c2++) af[c2] = *(const short8*)(Arow + c2*32);
  const int ntiles = Ncols >> 4;
  for (int ct = wid; ct < ntiles; ct += 4){
    f32x4 acc = {0.f,0.f,0.f,0.f};
    const short* Brow = (const short*)BT + (size_t)(ct*16+lr)*K + lg*8;
#pragma unroll
    for (int c2 = 0; c2 < KCH; c2++){
      short8 bfr = *(const short8*)(Brow + c2*32);
      acc = __builtin_amdgcn_mfma_f32_16x16x32_bf16(af[c2], bfr, acc, 0, 0, 0);
    }
    int col = ct*16 + lr;
    float bvv = bias ? bias[col]*bscale : 0.f;
#pragma unroll
    for (int r = 0; r < 4; r++){
      int row = row0 + lg*4 + r;
      size_t o = (size_t)row*ldc + col;
      float v = acc[r] + bvv;
      if (resid) v += resid[o];
      if (relu) v = fmaxf(v, 0.f);
      if (Cf) Cf[o] = v;
      if (Cb) Cb[o] = __float2bfloat16(v);
    }
  }
}

// ---------------- CSR build for gather-form GCN aggregation ----------------
__global__ void k_hist(const int* __restrict__ dst, int* __restrict__ cnt){
  int e = blockIdx.x*256 + threadIdx.x;
  if (e < EE) atomicAdd(&cnt[dst[e]], 1);
}

__global__ void k_scan(const int* __restrict__ cnt, int* __restrict__ off, int* __restrict__ woff){
  __shared__ int s[256];
  int t = threadIdx.x;
  int base = t*32;
  int local[32];
  int sum = 0;
#pragma unroll
  for (int i = 0; i < 32; i++){ local[i] = sum; sum += cnt[base+i]; }
  s[t] = sum;
  __syncthreads();
  if (t == 0){
    int run = 0;
    for (int i = 0; i < 256; i++){ int v = s[i]; s[i] = run; run += v; }
  }
  __syncthreads();
  int b = s[t];
#pragma unroll
  for (int i = 0; i < 32; i++){ off[base+i] = b + local[i]; woff[base+i] = b + local[i]; }
  if (t == 255) off[8192] = EE;
}

__global__ void k_fill(const int* __restrict__ dst, int* __restrict__ woff, int* __restrict__ elist){
  int e = blockIdx.x*256 + threadIdx.x;
  if (e < EE){
    int p = atomicAdd(&woff[dst[e]], 1);
    elist[p] = e;
  }
}

__global__ __launch_bounds__(256)
void k_degcsr(const int* __restrict__ off, const int* __restrict__ elist,
              const float* __restrict__ ew, float* __restrict__ dinv){
  int n = blockIdx.x*4 + (threadIdx.x >> 6);
  int lane = threadIdx.x & 63;
  int o0 = off[n], o1 = off[n+1];
  float s = 0.f;
  for (int j = o0 + lane; j < o1; j += 64) s += ew[elist[j]];
#pragma unroll
  for (int o = 32; o; o >>= 1) s += __shfl_xor(s, o, 64);
  if (lane == 0) dinv[n] = rsqrtf(s + 1.0f);
}

// gather aggregation, fused with y1 = agg + hw*dinv^2 + b_gcn + h
__global__ __launch_bounds__(256)
void k_gather(const int* __restrict__ off, const int* __restrict__ elist,
              const float* __restrict__ ew, const float* __restrict__ dinv,
              const float* __restrict__ hw, const float* __restrict__ h,
              const float* __restrict__ bgcn, float* __restrict__ y1){
  int n = blockIdx.x*4 + (threadIdx.x >> 6);
  int lane = threadIdx.x & 63;
  int o0 = off[n], o1 = off[n+1];
  float dn = dinv[n];
  f32x4 acc = {0.f,0.f,0.f,0.f};
  for (int j = o0; j < o1; j++){
    int e = elist[j];
    int s = e >> 5;
    float coef = dinv[s]*ew[e]*dn;
    f32x4 v = ((const f32x4*)(hw + (size_t)s*CH))[lane];
    acc[0] += v[0]*coef; acc[1] += v[1]*coef;
    acc[2] += v[2]*coef; acc[3] += v[3]*coef;
  }
  f32x4 hwn = ((const f32x4*)(hw + (size_t)n*CH))[lane];
  f32x4 hn  = ((const f32x4*)(h  + (size_t)n*CH))[lane];
  f32x4 bg  = ((const f32x4*)bgcn)[lane];
  float dd = dn*dn;
  f32x4 o;
  o[0] = acc[0] + hwn[0]*dd + bg[0] + hn[0];
  o[1] = acc[1] + hwn[1]*dd + bg[1] + hn[1];
  o[2] = acc[2] + hwn[2]*dd + bg[2] + hn[2];
  o[3] = acc[3] + hwn[3]*dd + bg[3] + hn[3];
  ((f32x4*)(y1 + (size_t)n*CH))[lane] = o;
}

// ---------------- bf16 transpose 8192x256 -> 256x8192 ----------------
__global__ __launch_bounds__(256)
void k_transpose(const bf16* __restrict__ in, bf16* __restrict__ out){
  __shared__ short tile[32][33];
  int bx = blockIdx.x & 7;
  int by = blockIdx.x >> 3;
  int tx = threadIdx.x & 31, ty = threadIdx.x >> 5;
  const short* inp = (const short*)in;
  short* outp = (short*)out;
#pragma unroll
  for (int i = 0; i < 4; i++)
    tile[ty + i*8][tx] = inp[(size_t)(by*32 + ty + i*8)*256 + bx*32 + tx];
  __syncthreads();
#pragma unroll
  for (int i = 0; i < 4; i++)
    outp[(size_t)(bx*32 + ty + i*8)*8192 + by*32 + tx] = tile[tx][ty + i*8];
}

// ---------------- flash attention v2: LDS-staged K/V tiles, 4-way key split ----------------
// grid = 512: bid = qt*4 + sp. Round-robin XCD dispatch puts one sp per XCD ->
// per-XCD K/V working set = 2MB, L2-resident. Block: 4 waves x 16 queries (QB=64),
// all waves share staged 32-key tiles. K tile [32][512B] and VT tile packed
// [128 rows][2 dims x 64B], both XOR-swizzled (applied on global src; gl_lds dest linear).
__global__ __launch_bounds__(256, 2)
void k_attn2(const bf16* __restrict__ Qm, const bf16* __restrict__ Km, const bf16* __restrict__ VT,
             bf16* __restrict__ Opart, float* __restrict__ Mpart, float* __restrict__ Lpart)
{
  __shared__ char lds[69632];   // 2 bufs x (16KB K + 16KB VT) + 4KB sP
  const int wid = threadIdx.x >> 6, lane = threadIdx.x & 63;
  const int lr = lane & 15, lg = lane >> 4;
  const int qt = blockIdx.x >> 2, sp = blockIdx.x & 3;
  const int q0 = qt*64 + wid*16;
  const int kbase = sp*2048;

  short8 qf[8];
  const short* Qrow = (const short*)Qm + (size_t)(q0+lr)*CH + lg*8;
#pragma unroll
  for (int c = 0; c < 8; c++) qf[c] = *(const short8*)(Qrow + c*32);

  f32x4 acc[16];
#pragma unroll
  for (int dt = 0; dt < 16; dt++) acc[dt] = {0.f,0.f,0.f,0.f};
  float m[4], ls[4];
#pragma unroll
  for (int r = 0; r < 4; r++){ m[r] = -1e30f; ls[r] = 0.f; }

  char* sPw = lds + 65536 + wid*1024;

  auto STAGE = [&](int buf, int t){
    const int k0 = kbase + t*32;
    char* base = lds + buf*32768;
#pragma unroll
    for (int i = 0; i < 4; i++){
      int L = wid*4096 + i*1024 + lane*16;
      {  // K tile: row r (key), 512B rows, swz byte^=((r&7)<<4)
        int r = L >> 9, b = L & 511;
        int bp = b ^ ((r&7)<<4);
        const char* src = (const char*)Km + ((size_t)(k0+r)*CH)*2 + bp;
        gl_lds16(src, base + wid*4096 + i*1024);
      }
      {  // VT tile: LDS row j holds dims {2j,2j+1} x 32 keys (64B each), swz byte^=((j&7)<<4)
        int j = L >> 7, b = L & 127;
        int bp = b ^ ((j&7)<<4);
        int dim = 2*j + (bp >= 64 ? 1 : 0);
        int kb = bp & 63;
        const char* src = (const char*)VT + ((size_t)dim*8192 + k0)*2 + kb;
        gl_lds16(src, base + 16384 + wid*4096 + i*1024);
      }
    }
  };

  STAGE(0, 0);
  __syncthreads();

  for (int t = 0; t < 64; t++){
    if (t + 1 < 64) STAGE((t+1)&1, t+1);
    const char* bK = lds + (t&1)*32768;
    const char* bV = bK + 16384;

    // QK^T: 16 queries x 32 keys
    f32x4 s0 = {0.f,0.f,0.f,0.f}, s1 = {0.f,0.f,0.f,0.f};
#pragma unroll
    for (int c = 0; c < 8; c++){
      int g = c*64 + lg*16;
      short8 kf0 = *(const short8*)(bK + lr*512 + (g ^ ((lr&7)<<4)));
      s0 = __builtin_amdgcn_mfma_f32_16x16x32_bf16(qf[c], kf0, s0, 0, 0, 0);
      short8 kf1 = *(const short8*)(bK + (16+lr)*512 + (g ^ ((lr&7)<<4)));
      s1 = __builtin_amdgcn_mfma_f32_16x16x32_bf16(qf[c], kf1, s1, 0, 0, 0);
    }
    // online softmax, exact defer-rescale
    float pm[4];
    int need = 0;
#pragma unroll
    for (int r = 0; r < 4; r++){
      float p = fmaxf(s0[r], s1[r]);
#pragma unroll
      for (int off = 1; off < 16; off <<= 1) p = fmaxf(p, __shfl_xor(p, off, 64));
      pm[r] = p;
      need |= (p > m[r]) ? 1 : 0;
    }
    if (__any(need)){
#pragma unroll
      for (int r = 0; r < 4; r++){
        float mn = fmaxf(m[r], pm[r]);
        float al = __expf(m[r] - mn);
        m[r] = mn;
        ls[r] *= al;
#pragma unroll
        for (int dt = 0; dt < 16; dt++) acc[dt][r] *= al;
      }
    }
#pragma unroll
    for (int r = 0; r < 4; r++){
      float p0 = __expf(s0[r] - m[r]);
      float p1 = __expf(s1[r] - m[r]);
      ls[r] += p0 + p1;
      int prow = lg*4 + r;
      *(short*)(sPw + (prow*32 + lr)*2)      = f2bf(p0);
      *(short*)(sPw + (prow*32 + 16 + lr)*2) = f2bf(p1);
    }
    __builtin_amdgcn_sched_barrier(0);
    short8 pf = *(const short8*)(sPw + (lr*32 + lg*8)*2);
    // PV: O += P @ V
#pragma unroll
    for (int dt = 0; dt < 16; dt++){
      int d = dt*16 + lr;
      int j = d >> 1;
      int gp = (d&1)*64 + lg*16;
      short8 vf = *(const short8*)(bV + j*128 + (gp ^ ((j&7)<<4)));
      acc[dt] = __builtin_amdgcn_mfma_f32_16x16x32_bf16(pf, vf, acc[dt], 0, 0, 0);
    }
    __syncthreads();
  }

#pragma unroll
  for (int r = 0; r < 4; r++){
#pragma unroll
    for (int off = 1; off < 16; off <<= 1) ls[r] += __shfl_xor(ls[r], off, 64);
  }
  size_t ob = (size_t)sp*NN*CH;
#pragma unroll
  for (int dt = 0; dt < 16; dt++){
#pragma unroll
    for (int r = 0; r < 4; r++){
      int row = q0 + lg*4 + r;
      Opart[ob + (size_t)row*CH + dt*16 + lr] = __float2bfloat16(acc[dt][r]);
    }
  }
  if (lr == 0){
#pragma unroll
    for (int r = 0; r < 4; r++){
      int row = q0 + lg*4 + r;
      Mpart[sp*NN + row] = m[r];
      Lpart[sp*NN + row] = ls[r];
    }
  }
}

__global__ __launch_bounds__(256)
void k_merge4(const bf16* __restrict__ Opart, const float* __restrict__ Mp,
              const float* __restrict__ Lp, bf16* __restrict__ out){
  int tid = blockIdx.x*256 + threadIdx.x;   // NN*32 threads, 8 cols each
  int q = tid >> 5;
  int cb = (tid & 31) * 8;
  float mx = Mp[q];
#pragma unroll
  for (int s = 1; s < 4; s++) mx = fmaxf(mx, Mp[s*NN + q]);
  float wt[4], den = 0.f;
#pragma unroll
  for (int s = 0; s < 4; s++){ wt[s] = __expf(Mp[s*NN + q] - mx); den += Lp[s*NN + q]*wt[s]; }
  float inv = 1.f / den;
  float o[8];
#pragma unroll
  for (int j = 0; j < 8; j++) o[j] = 0.f;
#pragma unroll
  for (int s = 0; s < 4; s++){
    short8 v = *(const short8*)((const short*)Opart + (size_t)s*NN*CH + (size_t)q*CH + cb);
    float f = wt[s];
#pragma unroll
    for (int j = 0; j < 8; j++) o[j] += bf2f(v[j]) * f;
  }
  short8 res;
#pragma unroll
  for (int j = 0; j < 8; j++) res[j] = f2bf(o[j]*inv);
  *(short8*)((short*)out + (size_t)q*CH + cb) = res;
}

// ---------------- link-prediction head ----------------
__global__ void k_content(const int* __restrict__ eli, const float* __restrict__ z3, bf16* __restrict__ outc){
  int idx = blockIdx.x*256 + threadIdx.x;
  int q = idx >> 8, c = idx & 255;
  int a = eli[q], b = eli[QQ + q];
  outc[idx] = __float2bfloat16(z3[(size_t)a*CH + c]*z3[(size_t)b*CH + c]);
}

__global__ __launch_bounds__(256)
void k_structure(const int* __restrict__ eli, const int* __restrict__ nbr,
                 const float* __restrict__ z3, const float* __restrict__ tptr, bf16* __restrict__ outs){
  __shared__ int tn[32];
  __shared__ int msk[32];
  int q = blockIdx.x;
  if (threadIdx.x < 32){
    int d = threadIdx.x;
    int a = nbr[(size_t)eli[q]*DD + d];
    int s = nbr[(size_t)eli[QQ+q]*DD + d];
    tn[d] = a;
    msk[d] = (a == s);
  }
  __syncthreads();
  int c = threadIdx.x;
  float tval = tptr[0];
  float vmax = -1e30f;
  float zg[32];
#pragma unroll
  for (int d = 0; d < 32; d++){
    float v = msk[d] ? z3[(size_t)tn[d]*CH + c] : 0.f;
    zg[d] = v;
    float sc = msk[d] ? tval*v : -1e30f;
    vmax = fmaxf(vmax, sc);
  }
  float esum = 0.f, wsum = 0.f;
#pragma unroll
  for (int d = 0; d < 32; d++){
    float e = msk[d] ? __expf(tval*zg[d] - vmax) : 0.f;
    esum += e;
    wsum += e*zg[d];
  }
  outs[(size_t)q*CH + c] = __float2bfloat16(wsum / fmaxf(esum, 1e-12f));
}

__global__ __launch_bounds__(256)
void k_final(const bf16* __restrict__ hmid, const float* __restrict__ w,
             const float* __restrict__ b, float* __restrict__ out){
  int r = blockIdx.x*4 + (threadIdx.x >> 6);
  int lane = threadIdx.x & 63;
  float s = 0.f;
#pragma unroll
  for (int i = 0; i < 4; i++){
    int c = lane + 64*i;
    s += __bfloat162float(hmid[(size_t)r*CH + c]) * w[c];
  }
#pragma unroll
  for (int off = 32; off; off >>= 1) s += __shfl_xor(s, off, 64);
  if (lane == 0) out[r] = s + b[0];
}

// =====================================================================
extern "C" void kernel_launch(void* const* d_in, const int* in_sizes, int n_in,
                              void* d_out, int out_size, void* d_ws, size_t ws_size,
                              hipStream_t stream)
{
  const float* x      = (const float*)d_in[0];
  const int*   eidx   = (const int*)d_in[1];
  const float* ew     = (const float*)d_in[2];
  const int*   eli    = (const int*)d_in[3];
  const int*   nbr    = (const int*)d_in[4];
  const float* pe_g   = (const float*)d_in[5];
  const float* pe_b   = (const float*)d_in[6];
  const float* W_pe   = (const float*)d_in[7];
  const float* b_pe   = (const float*)d_in[8];
  const float* W_gcn  = (const float*)d_in[9];
  const float* b_gcn  = (const float*)d_in[10];
  const float* bn1_g  = (const float*)d_in[11];
  const float* bn1_b  = (const float*)d_in[12];
  const float* Wq     = (const float*)d_in[13];
  const float* bq     = (const float*)d_in[14];
  const float* Wk     = (const float*)d_in[15];
  const float* bk     = (const float*)d_in[16];
  const float* Wv     = (const float*)d_in[17];
  const float* bvv    = (const float*)d_in[18];
  const float* Wo     = (const float*)d_in[19];
  const float* bo     = (const float*)d_in[20];
  const float* bn2_g  = (const float*)d_in[21];
  const float* bn2_b  = (const float*)d_in[22];
  const float* W_m1   = (const float*)d_in[23];
  const float* b_m1   = (const float*)d_in[24];
  const float* W_m2   = (const float*)d_in[25];
  const float* b_m2   = (const float*)d_in[26];
  const float* bn3_g  = (const float*)d_in[27];
  const float* bn3_b  = (const float*)d_in[28];
  const float* W_cm   = (const float*)d_in[29];
  const float* b_cm   = (const float*)d_in[30];
  const float* W_sm   = (const float*)d_in[31];
  const float* b_sm   = (const float*)d_in[32];
  const float* W_o1   = (const float*)d_in[33];
  const float* b_o1   = (const float*)d_in[34];
  const float* bno_g  = (const float*)d_in[35];
  const float* bno_b  = (const float*)d_in[36];
  const float* W_o2   = (const float*)d_in[37];
  const float* b_o2   = (const float*)d_in[38];
  const float* tptr   = (const float*)d_in[39];

  if (ws_size < 64*MBYTE) return;
  char* ws = (char*)d_ws;

  bf16* WpeT  = (bf16*)(ws + 0);
  bf16* WgcnT = (bf16*)(ws + 64*1024);
  bf16* WqT   = (bf16*)(ws + 192*1024);
  bf16* WkT   = (bf16*)(ws + 320*1024);
  bf16* WvT   = (bf16*)(ws + 448*1024);
  bf16* WoT   = (bf16*)(ws + 576*1024);
  bf16* Wm1T  = (bf16*)(ws + 704*1024);
  bf16* Wm2T  = (bf16*)(ws + 960*1024);
  bf16* WcmT  = (bf16*)(ws + 1216*1024);
  bf16* WsmT  = (bf16*)(ws + 1344*1024);
  bf16* Wo1T  = (bf16*)(ws + 1472*1024);
  float* stat_x = (float*)(ws + 2*MBYTE);
  float* stat1  = (float*)(ws + 2*MBYTE + 1024);
  float* stat2  = (float*)(ws + 2*MBYTE + 3*1024);
  float* stat3  = (float*)(ws + 2*MBYTE + 5*1024);
  float* stato  = (float*)(ws + 2*MBYTE + 7*1024);
  float* deg    = (float*)(ws + 2*MBYTE + 16*1024);
  float* Mpart  = (float*)(ws + 2*MBYTE + 256*1024);  // 4*NN f32 = 128KB
  float* Lpart  = (float*)(ws + 2*MBYTE + 512*1024);  // 128KB
  bf16*  xn    = (bf16*)(ws + 4*MBYTE);
  float* hbuf  = (float*)(ws + 8*MBYTE);
  bf16*  hb    = (bf16*)(ws + 16*MBYTE);
  float* hw    = (float*)(ws + 20*MBYTE);
  float* aggb  = (float*)(ws + 28*MBYTE);
  float* h1    = (float*)(ws + 36*MBYTE);
  bf16*  qb    = (bf16*)(ws + 44*MBYTE);
  bf16*  kb    = (bf16*)(ws + 48*MBYTE);
  bf16*  vb    = (bf16*)(ws + 52*MBYTE);
  bf16*  vT    = (bf16*)(ws + 56*MBYTE);
  bf16*  OpartB= (bf16*)(ws + 20*MBYTE);   // 4 splits x 4MB bf16, over dead hw/aggb
  bf16*  attnb = (bf16*)(ws + 16*MBYTE);
  float* y2    = hbuf;
  float* zf    = (float*)(ws + 44*MBYTE);
  bf16*  zb    = (bf16*)(ws + 52*MBYTE);
  bf16*  midb  = (bf16*)(ws + 56*MBYTE);
  float* y3    = (float*)(ws + 20*MBYTE);
  float* z3    = (float*)(ws + 28*MBYTE);
  bf16*  z3b   = (bf16*)(ws + 8*MBYTE);
  bf16*  contb = (bf16*)(ws + 4*MBYTE);
  bf16*  strub = (bf16*)(ws + 12*MBYTE);
  bf16*  hcat  = (bf16*)(ws + 16*MBYTE);
  float* y4    = (float*)(ws + 36*MBYTE);
  bf16*  hmid  = (bf16*)(ws + 40*MBYTE);

  int* cnt   = (int*)(ws + 44*MBYTE);
  int* off   = (int*)(ws + 44*MBYTE + 32*1024);
  int* woff  = (int*)(ws + 44*MBYTE + 96*1024);
  int* elist = (int*)(ws + 44*MBYTE + 128*1024);

  const int* dstp = eidx + EE;

  k_zero<<<(12288 + 8192 + 255)/256, 256, 0, stream>>>((float*)(ws + 2*MBYTE), 12288, (float*)cnt, 8192);

  // weight prep (Wq/bq pre-scaled by 1/sqrt(C)=1/16)
  k_wconv<<<128, 256, 0, stream>>>(W_pe, WpeT, 128, 256, 1.f);
  k_wconv<<<256, 256, 0, stream>>>(W_gcn, WgcnT, 256, 256, 1.f);
  k_wconv<<<256, 256, 0, stream>>>(Wq, WqT, 256, 256, 0.0625f);
  k_wconv<<<256, 256, 0, stream>>>(Wk, WkT, 256, 256, 1.f);
  k_wconv<<<256, 256, 0, stream>>>(Wv, WvT, 256, 256, 1.f);
  k_wconv<<<256, 256, 0, stream>>>(Wo, WoT, 256, 256, 1.f);
  k_wconv<<<512, 256, 0, stream>>>(W_m1, Wm1T, 256, 512, 1.f);
  k_wconv<<<512, 256, 0, stream>>>(W_m2, Wm2T, 512, 256, 1.f);
  k_wconv<<<256, 256, 0, stream>>>(W_cm, WcmT, 256, 256, 1.f);
  k_wconv<<<256, 256, 0, stream>>>(W_sm, WsmT, 256, 256, 1.f);
  k_wconv<<<512, 256, 0, stream>>>(W_o1, Wo1T, 512, 256, 1.f);

  // CSR build
  k_hist<<<EE/256, 256, 0, stream>>>(dstp, cnt);
  k_scan<<<1, 256, 0, stream>>>(cnt, off, woff);
  k_fill<<<EE/256, 256, 0, stream>>>(dstp, woff, elist);
  k_degcsr<<<NN/4, 256, 0, stream>>>(off, elist, ew, deg);

  // input BN -> xn (bf16)
  k_bnstats<<<256, 128, 0, stream>>>(x, stat_x, NN, CINN);
  k_bnapply<<<NN*CINN/256, 256, 0, stream>>>(x, stat_x, pe_g, pe_b, nullptr, nullptr, xn, NN, CINN-1, 0);

  // h = xn @ W_pe + b_pe
  k_gemm<4><<<NN/16, 256, 0, stream>>>(xn, WpeT, b_pe, nullptr, hbuf, hb, 256, 256, 0, 1.f);

  // hw = h @ W_gcn
  k_gemm<8><<<NN/16, 256, 0, stream>>>(hb, WgcnT, nullptr, nullptr, hw, nullptr, 256, 256, 0, 1.f);

  // gather aggregation fused with y1
  k_gather<<<NN/4, 256, 0, stream>>>(off, elist, ew, deg, hw, hbuf, b_gcn, aggb);

  // bn1 -> h1
  k_bnstats<<<256, 256, 0, stream>>>(aggb, stat1, NN, CH);
  k_bnapply<<<NN*CH/256, 256, 0, stream>>>(aggb, stat1, bn1_g, bn1_b, nullptr, h1, nullptr, NN, CH-1, 0);

  // q (pre-scaled), k, v
  k_gemm<8><<<NN/16, 256, 0, stream>>>(hb, WqT, bq, nullptr, nullptr, qb, 256, 256, 0, 0.0625f);
  k_gemm<8><<<NN/16, 256, 0, stream>>>(hb, WkT, bk, nullptr, nullptr, kb, 256, 256, 0, 1.f);
  k_gemm<8><<<NN/16, 256, 0, stream>>>(hb, WvT, bvv, nullptr, nullptr, vb, 256, 256, 0, 1.f);
  k_transpose<<<2048, 256, 0, stream>>>(vb, vT);

  // attention: LDS-staged tiles, 4-way key split, cross-block merge
  k_attn2<<<512, 256, 0, stream>>>(qb, kb, vT, OpartB, Mpart, Lpart);
  k_merge4<<<NN*32/256, 256, 0, stream>>>(OpartB, Mpart, Lpart, attnb);

  // y2 = attn @ Wo + bo + h  (in-place over h)
  k_gemm<8><<<NN/16, 256, 0, stream>>>(attnb, WoT, bo, hbuf, hbuf, nullptr, 256, 256, 0, 1.f);

  // z = h1 + bn2(y2)
  k_bnstats<<<256, 256, 0, stream>>>(y2, stat2, NN, CH);
  k_bnapply<<<NN*CH/256, 256, 0, stream>>>(y2, stat2, bn2_g, bn2_b, h1, zf, zb, NN, CH-1, 0);

  // MLP
  k_gemm<8><<<NN/16, 256, 0, stream>>>(zb, Wm1T, b_m1, nullptr, nullptr, midb, 512, 512, 1, 1.f);
  k_gemm<16><<<NN/16, 256, 0, stream>>>(midb, Wm2T, b_m2, zf, y3, nullptr, 256, 256, 0, 1.f);

  // bn3 -> z3
  k_bnstats<<<256, 256, 0, stream>>>(y3, stat3, NN, CH);
  k_bnapply<<<NN*CH/256, 256, 0, stream>>>(y3, stat3, bn3_g, bn3_b, nullptr, z3, z3b, NN, CH-1, 0);

  // head
  k_content<<<QQ*CH/256, 256, 0, stream>>>(eli, z3, contb);
  k_structure<<<QQ, 256, 0, stream>>>(eli, nbr, z3, tptr, strub);

  k_gemm<8><<<QQ/16, 256, 0, stream>>>(contb, WcmT, b_cm, nullptr, nullptr, hcat, 256, 512, 0, 1.f);
  k_gemm<8><<<QQ/16, 256, 0, stream>>>(strub, WsmT, b_sm, nullptr, nullptr, hcat + 256, 256, 512, 0, 1.f);

  k_gemm<16><<<QQ/16, 256, 0, stream>>>(hcat, Wo1T, b_o1, nullptr, y4, nullptr, 256, 256, 0, 1.f);
  k_bnstats<<<256, 256, 0, stream>>>(y4, stato, QQ, CH);
  k_bnapply<<<QQ*CH/256, 256, 0, stream>>>(y4, stato, bno_g, bno_b, nullptr, nullptr, hmid, QQ, CH-1, 1);

  k_final<<<QQ/4, 256, 0, stream>>>(hmid, W_o2, b_o2, (float*)d_out);
}